// Round 4
// baseline (970.354 us; speedup 1.0000x reference)
//
#include <hip/hip_runtime.h>

typedef unsigned short u16;
typedef short bf16x8 __attribute__((ext_vector_type(8)));   // MFMA A/B frag (8 bf16)
typedef float f32x4  __attribute__((ext_vector_type(4)));   // MFMA C/D frag
typedef u16   u16x8  __attribute__((ext_vector_type(8)));   // 16B vector ld/st

#define MFMA_BF16(a, b, c) __builtin_amdgcn_mfma_f32_16x16x32_bf16((a), (b), (c), 0, 0, 0)

#define B_  8
#define L_  2500
#define LP  2528          // L padded to 79*32
#define E_  100
#define F_  50
#define Y_  8922
#define YP  8960          // Y padded to 280*32
#define KT_ 280           // K tiles of 32 over YP
#define NT_ 416           // N = B*F = 400 padded to 26*16
#define KP_ 4             // K-split for adj GEMM (280/4 = 70 tiles per part)
#define AMAX_ (Y_ * Y_ - 1)

__device__ __forceinline__ u16 f2bf(float f) {
    unsigned int x = __float_as_uint(f);
    unsigned int r = x + 0x7fffu + ((x >> 16) & 1u);   // RNE
    return (u16)(r >> 16);
}

// direct global->LDS copies (wave-uniform LDS base + lane*size, per-lane global src)
__device__ __forceinline__ void glds16(const void* g, const void* l) {
    __builtin_amdgcn_global_load_lds(
        (const __attribute__((address_space(1))) unsigned int*)(unsigned long long)g,
        (__attribute__((address_space(3))) unsigned int*)(unsigned int)(unsigned long long)l,
        16, 0, 0);
}
__device__ __forceinline__ void glds4(const void* g, const void* l) {
    __builtin_amdgcn_global_load_lds(
        (const __attribute__((address_space(1))) unsigned int*)(unsigned long long)g,
        (__attribute__((address_space(3))) unsigned int*)(unsigned int)(unsigned long long)l,
        4, 0, 0);
}

// ---------------------------------------------------------------- prep
__global__ __launch_bounds__(256) void k0_prep(
    const int* __restrict__ x, const float* __restrict__ conv_w,
    int* __restrict__ flag, float* __restrict__ wT)
{
    const int k = blockIdx.x;           // 0..8
    const int tid = threadIdx.x;
    if (k == 0 && tid == 0) {
        int nz = 0;
        #pragma unroll
        for (int i = 0; i < 32; i++) nz |= x[2 * i + 1];
        *flag = (nz == 0) ? 1 : 0;      // all-high-words-zero => int64 buffer
    }
    for (int j = tid; j < 5000; j += 256)           // j = f*100 + e
        wT[k * 5000 + j] = conv_w[j * 9 + k];
}

// ---------------------------------------------------------------- conv (fp32, LDS-staged weights)
__global__ __launch_bounds__(256) void k1_conv(
    const int* __restrict__ x, const int* __restrict__ flag,
    const float* __restrict__ embed_w, const float* __restrict__ wT,
    const float* __restrict__ conv_b,
    u16* __restrict__ hp, u16* __restrict__ hpT)
{
    __shared__ float sEmb[72 * 104];   // 72 rows (64 + 8 halo), stride 104
    __shared__ float sW[50 * 104];     // per-k weight slice [f][e], stride 104
    __shared__ int   sId[72];
    const int tid = threadIdx.x;
    const int b  = blockIdx.y;
    const int l0 = blockIdx.x * 64;
    const int is64 = *flag;

    if (tid < 72) {
        int l = l0 - 4 + tid;
        int id = -1;
        if (l >= 0 && l < L_) id = is64 ? x[(b * L_ + l) * 2] : x[b * L_ + l];
        sId[tid] = id;
    }
    __syncthreads();
    for (int i = tid; i < 72 * 25; i += 256) {       // float4 granules
        int r = i / 25, e4 = i - r * 25;
        int id = sId[r];
        float4 v = make_float4(0.f, 0.f, 0.f, 0.f);
        if (id >= 0) v = *(const float4*)&embed_w[(size_t)id * 100 + e4 * 4];
        *(float4*)&sEmb[r * 104 + e4 * 4] = v;
    }

    const int li = tid & 63;
    const int fg = __builtin_amdgcn_readfirstlane(tid >> 6);   // wave-uniform f-group 0..3

    float acc[13];
    #pragma unroll
    for (int i = 0; i < 13; i++) { int f = fg + 4 * i; acc[i] = (f < F_) ? conv_b[f] : 0.f; }

    for (int k = 0; k < 9; k++) {
        __syncthreads();
        for (int i = tid; i < 1250; i += 256) {      // stage wT[k] : 50 f x 25 float4
            int f = i / 25, e4 = i - f * 25;
            *(float4*)&sW[f * 104 + e4 * 4] = *(const float4*)&wT[k * 5000 + f * 100 + e4 * 4];
        }
        __syncthreads();
        for (int e4 = 0; e4 < 25; e4++) {
            float4 h = *(const float4*)&sEmb[(li + k) * 104 + e4 * 4];
            #pragma unroll
            for (int i = 0; i < 13; i++) {
                int f = fg + 4 * i;
                if (f < F_) {
                    float4 w = *(const float4*)&sW[f * 104 + e4 * 4];   // uniform -> LDS broadcast
                    acc[i] += h.x * w.x + h.y * w.y + h.z * w.z + h.w * w.w;
                }
            }
        }
    }

    int l = l0 + li;
    if (l < LP) {
        bool valid = (l < L_);
        #pragma unroll
        for (int i = 0; i < 13; i++) {
            int f = fg + 4 * i;
            if (f < F_) {
                u16 hv = 0;
                if (valid) {
                    float e2 = __expf(2.f * acc[i]);
                    hv = f2bf((e2 - 1.f) / (e2 + 1.f));   // tanh
                }
                hp [((size_t)b * LP + l) * 64 + f] = hv;
                hpT[((size_t)b * 64 + f) * LP + l] = hv;
            }
        }
        #pragma unroll
        for (int j = 0; j < 4; j++) {
            int f = 50 + fg + 4 * j;
            if (f < 64) {
                hp [((size_t)b * LP + l) * 64 + f] = 0;
                hpT[((size_t)b * 64 + f) * LP + l] = (f == 50 && valid) ? f2bf(1.f) : (u16)0;
            }
        }
    }
}

// ---------------------------------------------------------------- flash attention (reg-prefetch pipelined)
__global__ __launch_bounds__(256) void k2_attn(
    const float* __restrict__ U4_w,
    const u16* __restrict__ hp, const u16* __restrict__ hpT,
    float* __restrict__ m4t)
{
    __shared__ u16  sU4[128 * 72];   // [y][f] f-contig, rows padded 72
    __shared__ u16  sHp[32 * 72];    // [l][f] f-contig (S-GEMM B)
    __shared__ u16  sHt[64 * 40];    // [f][l] l-contig (PV B), rows padded 40
    __shared__ u16  sP [128 * 40];   // [y][l] l-contig (PV A)
    __shared__ float sDen[128];

    const int tid  = threadIdx.x;
    const int b    = blockIdx.y;
    const int y0   = blockIdx.x * 128;
    const int w    = tid >> 6;
    const int lane = tid & 63;
    const int l15  = lane & 15;
    const int quad = lane >> 4;

    for (int i = tid; i < 128 * 72; i += 256) {
        int r = i / 72, c = i - r * 72;
        float v = 0.f;
        int y = y0 + r;
        if (c < F_ && y < Y_) v = U4_w[y * F_ + c];
        sU4[i] = f2bf(v);
    }
    __syncthreads();

    bf16x8 fa[2][2];   // hoisted U4 A-frags
    #pragma unroll
    for (int mi = 0; mi < 2; mi++)
        #pragma unroll
        for (int ks = 0; ks < 2; ks++)
            fa[mi][ks] = *(const bf16x8*)&sU4[(w * 32 + mi * 16 + l15) * 72 + ks * 32 + quad * 8];

    const f32x4 fz = {0.f, 0.f, 0.f, 0.f};
    f32x4 pacc[2][4];
    #pragma unroll
    for (int mi = 0; mi < 2; mi++)
        #pragma unroll
        for (int ni = 0; ni < 4; ni++) pacc[mi][ni] = fz;

    // staging coords + prefetch regs
    const int rr = tid >> 3, seg = tid & 7;      // hp tile [32][64]
    const int fr = tid >> 2, s2 = tid & 3;       // hpT tile [64][32]
    u16x8 pv, pv2;
    {
        pv  = *(const u16x8*)&hp [((size_t)b * LP + rr) * 64 + seg * 8];
        pv2 = *(const u16x8*)&hpT[((size_t)b * 64 + fr) * LP + s2 * 8];
    }

    for (int lt = 0; lt < 79; lt++) {
        const int l0 = lt * 32;
        __syncthreads();
        *(u16x8*)&sHp[rr * 72 + seg * 8] = pv;
        *(u16x8*)&sHt[fr * 40 + s2 * 8] = pv2;
        if (lt + 1 < 79) {   // prefetch next tile; latency hidden under S+PV compute
            const int ln = l0 + 32;
            pv  = *(const u16x8*)&hp [((size_t)b * LP + ln + rr) * 64 + seg * 8];
            pv2 = *(const u16x8*)&hpT[((size_t)b * 64 + fr) * LP + ln + s2 * 8];
        }
        __syncthreads();

        // S = U4p [y×64f] · hp^T [64f×l]
        f32x4 sacc[2][2];
        #pragma unroll
        for (int mi = 0; mi < 2; mi++)
            #pragma unroll
            for (int ni = 0; ni < 2; ni++) sacc[mi][ni] = fz;
        #pragma unroll
        for (int ks = 0; ks < 2; ks++) {
            #pragma unroll
            for (int ni = 0; ni < 2; ni++) {
                bf16x8 fb = *(const bf16x8*)&sHp[(ni * 16 + l15) * 72 + ks * 32 + quad * 8];
                #pragma unroll
                for (int mi = 0; mi < 2; mi++)
                    sacc[mi][ni] = MFMA_BF16(fa[mi][ks], fb, sacc[mi][ni]);
            }
        }
        // P = exp(S), write to LDS in A-layout
        #pragma unroll
        for (int mi = 0; mi < 2; mi++)
            #pragma unroll
            for (int ni = 0; ni < 2; ni++) {
                int lcol = ni * 16 + l15;
                bool lv = (l0 + lcol) < L_;
                #pragma unroll
                for (int r = 0; r < 4; r++) {
                    float p = lv ? __expf(sacc[mi][ni][r]) : 0.f;
                    sP[(w * 32 + mi * 16 + quad * 4 + r) * 40 + lcol] = f2bf(p);
                }
            }
        __syncthreads();

        // O += P [y×32l] · hp [32l×64f]
        bf16x8 fv[4];
        #pragma unroll
        for (int ni = 0; ni < 4; ni++)
            fv[ni] = *(const bf16x8*)&sHt[(ni * 16 + l15) * 40 + quad * 8];
        #pragma unroll
        for (int mi = 0; mi < 2; mi++) {
            bf16x8 fp_ = *(const bf16x8*)&sP[(w * 32 + mi * 16 + l15) * 40 + quad * 8];
            #pragma unroll
            for (int ni = 0; ni < 4; ni++)
                pacc[mi][ni] = MFMA_BF16(fp_, fv[ni], pacc[mi][ni]);
        }
    }

    // denominator column: f=50 -> ni=3, lane&15==2
    if (l15 == 2) {
        #pragma unroll
        for (int mi = 0; mi < 2; mi++)
            #pragma unroll
            for (int r = 0; r < 4; r++)
                sDen[w * 32 + mi * 16 + quad * 4 + r] = pacc[mi][3][r];
    }
    __syncthreads();

    #pragma unroll
    for (int mi = 0; mi < 2; mi++)
        #pragma unroll
        for (int ni = 0; ni < 4; ni++) {
            int f = ni * 16 + l15;
            if (f < F_) {
                #pragma unroll
                for (int r = 0; r < 4; r++) {
                    int yl = w * 32 + mi * 16 + quad * 4 + r;
                    int y = y0 + yl;
                    if (y < Y_)
                        m4t[((size_t)b * Y_ + y) * F_ + f] = pacc[mi][ni][r] / sDen[yl];
                }
            }
        }
}

// ---------------------------------------------------------------- support + y4t
// Bt tile image (per kt): u16[416*32], PRE-SWIZZLED so that k4's linear
// global_load_lds image gives conflict-free ds_read_b128:
//   image[n*32 + ((z>>3) ^ ((n>>1)&3))*8 + (z&7)] = bf16(support[n][z])
__global__ __launch_bounds__(256) void k3_support(
    const float* __restrict__ m4t, const float* __restrict__ gcn_w,
    const float* __restrict__ f4t_w, const float* __restrict__ f4t_b,
    u16* __restrict__ Bt, float* __restrict__ y4t_out)
{
    __shared__ float sW[50 * 52];   // gcn_w^T : [g][f], rows padded 52
    const int tid = threadIdx.x;
    for (int i = tid; i < 50 * 52; i += 256) {
        int g = i / 52, f = i - g * 52;
        sW[i] = (f < F_) ? gcn_w[f * F_ + g] : 0.f;
    }
    __syncthreads();

    const int b = blockIdx.y;
    const int y = blockIdx.x * 256 + tid;
    if (y >= Y_) return;

    float2 m[25];
    const float* mrow = m4t + ((size_t)b * Y_ + y) * F_;
    #pragma unroll
    for (int i = 0; i < 25; i++) m[i] = *(const float2*)(mrow + 2 * i);

    const int kt = y >> 5, zo = y & 31;
    const int zhi = zo >> 3, zlo = zo & 7;
    u16* btile = Bt + (size_t)kt * (NT_ * 32);
    for (int g = 0; g < F_; g++) {
        float s = 0.f;
        const float* wr = sW + g * 52;
        #pragma unroll
        for (int i = 0; i < 25; i++) {
            float2 wv = *(const float2*)(wr + 2 * i);
            s += m[i].x * wv.x + m[i].y * wv.y;
        }
        int n = b * F_ + g;
        btile[n * 32 + ((zhi ^ ((n >> 1) & 3)) << 3) + zlo] = f2bf(s);
    }

    const float* tw = f4t_w + (size_t)y * F_;
    float acc = f4t_b[y];
    #pragma unroll
    for (int i = 0; i < 25; i++) {
        float2 wv = *(const float2*)(tw + 2 * i);
        acc += m[i].x * wv.x + m[i].y * wv.y;
    }
    y4t_out[(size_t)b * Y_ + y] = acc;
}

// ---------------------------------------------------------------- adj GEMM
// Asymmetric-depth counted-vmcnt pipeline:
//   A (adj, HBM stream, long tail latency): 3 buffers -> staged 2 tiles ahead
//   B (Bt, L2-resident 1.86MB/kp slice):    2 buffers -> staged 1 tile ahead
// Every iteration issues exactly B(t+1)[8] + A(t+2)[8] (kt clamped at the last
// tile; dummy loads land in provably-dead buffers since (t+2)%3 != t%3,(t+1)%3
// and (t+1)&1 != t&1). In-order vmcnt retirement (m135) makes one constant
//   s_waitcnt vmcnt(24)   <- newer items: A(t+1)[8]+B(t+1)[8]+A(t+2)[8]
// prove both B(t) and A(t) have landed. No vmcnt(0) drain in the loop, so the
// adj load tail gets 2 full tile-steps of cover instead of 1.
// sched_barrier(0) after EACH raw s_barrier: LLVM's s_barrier carries no
// memory effects, so without the fence next-iter glds issues could hoist
// between lgkmcnt(0) and the barrier and overwrite a buffer still being read.
__global__ __launch_bounds__(256, 2) void k4_gemm(
    const float* __restrict__ adj, const u16* __restrict__ Bt,
    float* __restrict__ outp)
{
    __shared__ float sA[3][64 * 32];    // fp32 A-tiles (swizzled image), 3x8 KB
    __shared__ u16   sB[2][NT_ * 32];   // bf16 B-tiles (pre-swizzled image), 2x26 KB
                                        // total 76 KB -> 2 blocks/CU

    const int tid  = threadIdx.x;
    const int bid  = blockIdx.x;
    const int xcd  = bid & 7;
    const int kp   = xcd >> 1;                      // 0..3
    const int mIdx = (bid >> 3) * 2 + (xcd & 1);    // 0..139 (bijective for grid 560)
    const int m0   = mIdx * 64;
    const int w    = tid >> 6;
    const int wq   = __builtin_amdgcn_readfirstlane(w);
    const int lane = tid & 63;
    const int l15  = lane & 15;
    const int quad = lane >> 4;
    const int wm   = w & 1;        // M sub-block (0..1) -> rows wm*32..+32
    const int wn   = w >> 1;       // N half (0..1) -> cols wn*208..+208

    // A staging: round j, thread t fills physical word j*256+t = (row, cphys).
    // logical col = ((cphys>>2) ^ (row&7))*4 + (cphys&3); row&7 == tid>>5 for all rounds.
    const int rA   = tid >> 5;                                       // 0..7
    const int colA = ((((tid & 31) >> 2) ^ rA) << 2) | (tid & 3);    // 0..31, round-invariant
    const unsigned rbaseA = (unsigned)(m0 + rA) * (unsigned)Y_ + (unsigned)colA;

    // lane-const swizzled read offsets
    const int r7    = l15 & 7;
    const int offA0 = (((2 * quad)     ^ r7) << 2);   // float offset of 1st 16B slot
    const int offA1 = (((2 * quad + 1) ^ r7) << 2);   // float offset of 2nd 16B slot
    const int offB  = ((quad ^ ((l15 >> 1) & 3)) << 3); // u16 offset of B slot

    const f32x4 fz = {0.f, 0.f, 0.f, 0.f};
    f32x4 acc[2][13];
    #pragma unroll
    for (int mi = 0; mi < 2; mi++)
        #pragma unroll
        for (int ni = 0; ni < 13; ni++) acc[mi][ni] = fz;

    // B stage = 8 loads/wave (6x glds16 + 2x glds4); A stage = 8 loads/wave (glds4)
    auto stageB = [&](int buf, int kt) {
        const char* bt = (const char*)Bt + (size_t)kt * (NT_ * 32 * 2);
        char* sb = (char*)sB[buf];
        #pragma unroll
        for (int j = 0; j < 6; j++)
            glds16(bt + j * 4096 + tid * 16, sb + j * 4096 + wq * 1024);
        #pragma unroll
        for (int j = 0; j < 2; j++)
            glds4(bt + 24576 + j * 1024 + tid * 4, sb + 24576 + j * 1024 + wq * 256);
    };
    auto stageA = [&](int buf, int kt) {
        char* sa = (char*)sA[buf];
        const unsigned idx0 = rbaseA + (unsigned)kt * 32u;
        #pragma unroll
        for (int j = 0; j < 8; j++) {
            unsigned idx = idx0 + (unsigned)(j * 8 * Y_);
            idx = (idx > (unsigned)AMAX_) ? (unsigned)AMAX_ : idx;   // OOB clamp (harmless rows/cols)
            glds4(adj + idx, sa + j * 1024 + wq * 256);
        }
    };

    const int kt0 = kp * 70, ktmax = kt0 + 69;
    // prologue issue order (vmcnt accounting depends on it): B0[8], A0[8], A1[8]
    stageB(0, kt0);
    stageA(0, kt0);
    stageA(1, kt0 + 1);

    int a0 = 0;   // A buffer index = t % 3
    for (int it = 0; it < 70; it++) {
        int ktb = kt0 + it + 1; if (ktb > ktmax) ktb = ktmax;
        int kta = kt0 + it + 2; if (kta > ktmax) kta = ktmax;
        stageB((it + 1) & 1, ktb);
        int a2 = a0 + 2; if (a2 >= 3) a2 -= 3;
        stageA(a2, kta);
        asm volatile("s_waitcnt vmcnt(24)" ::: "memory");   // B(t), A(t) landed
        __builtin_amdgcn_s_barrier();            // raw: no compiler drain
        __builtin_amdgcn_sched_barrier(0);

        const float* sAc = sA[a0];
        const u16*   sBc = sB[it & 1];
        bf16x8 fa[2];
        #pragma unroll
        for (int mi = 0; mi < 2; mi++) {
            const int rb = (wm * 32 + mi * 16 + l15) * 32;
            f32x4 x0 = *(const f32x4*)&sAc[rb + offA0];
            f32x4 x1 = *(const f32x4*)&sAc[rb + offA1];
            bf16x8 v;
            v[0] = (short)f2bf(x0[0]); v[1] = (short)f2bf(x0[1]);
            v[2] = (short)f2bf(x0[2]); v[3] = (short)f2bf(x0[3]);
            v[4] = (short)f2bf(x1[0]); v[5] = (short)f2bf(x1[1]);
            v[6] = (short)f2bf(x1[2]); v[7] = (short)f2bf(x1[3]);
            fa[mi] = v;
        }
        #pragma unroll
        for (int ni = 0; ni < 13; ni++) {
            bf16x8 fb = *(const bf16x8*)&sBc[(wn * 208 + ni * 16 + l15) * 32 + offB];
            acc[0][ni] = MFMA_BF16(fa[0], fb, acc[0][ni]);
            acc[1][ni] = MFMA_BF16(fa[1], fb, acc[1][ni]);
        }

        __builtin_amdgcn_sched_barrier(0);
        asm volatile("s_waitcnt lgkmcnt(0)" ::: "memory");   // reads of this tile done
        __builtin_amdgcn_s_barrier();            // raw: buffers free for overwrite
        __builtin_amdgcn_sched_barrier(0);       // pin next-iter glds below the barrier
        a0++; if (a0 >= 3) a0 = 0;
    }
    asm volatile("s_waitcnt vmcnt(0)" ::: "memory");   // drain dummy in-flight loads
    __builtin_amdgcn_sched_barrier(0);

    float* dst = outp + (size_t)kp * Y_ * 400;
    #pragma unroll
    for (int mi = 0; mi < 2; mi++)
        #pragma unroll
        for (int ni = 0; ni < 13; ni++) {
            int n = wn * 208 + ni * 16 + l15;
            if (n < 400) {
                #pragma unroll
                for (int r4 = 0; r4 < 4; r4++) {
                    int y = m0 + wm * 32 + mi * 16 + quad * 4 + r4;
                    if (y < Y_) dst[(size_t)y * 400 + n] = acc[mi][ni][r4];
                }
            }
        }
}

// ---------------------------------------------------------------- final y4
__global__ __launch_bounds__(256) void k5_final(
    const float* __restrict__ outp, const float* __restrict__ m4t,
    const float* __restrict__ gcn_b, const float* __restrict__ f4_w,
    const float* __restrict__ f4_b, float* __restrict__ y4_out)
{
    const int b = blockIdx.y;
    const int y = blockIdx.x * 256 + threadIdx.x;
    if (y >= Y_) return;

    const size_t PS = (size_t)Y_ * 400;
    const float* p0 = outp + (size_t)y * 400 + b * F_;
    const float* fw = f4_w + (size_t)y * 100;
    const float* mrow = m4t + ((size_t)b * Y_ + y) * F_;

    float acc = f4_b[y];
    #pragma unroll
    for (int i = 0; i < 25; i++) {
        float2 mv = *(const float2*)(mrow + 2 * i);
        float2 wv = *(const float2*)(fw + 2 * i);
        acc += mv.x * wv.x + mv.y * wv.y;
    }
    #pragma unroll
    for (int i = 0; i < 25; i++) {
        float sx = 0.f, sy = 0.f;
        #pragma unroll
        for (int kp = 0; kp < KP_; kp++) {
            float2 v = *(const float2*)(p0 + kp * PS + 2 * i);
            sx += v.x; sy += v.y;
        }
        float2 gb = *(const float2*)(gcn_b + 2 * i);
        sx += gb.x; sy += gb.y;
        sx = sx > 0.f ? sx : 0.2f * sx;   // leaky_relu
        sy = sy > 0.f ? sy : 0.2f * sy;
        float2 wv = *(const float2*)(fw + 50 + 2 * i);
        acc += sx * wv.x + sy * wv.y;
    }
    y4_out[(size_t)b * Y_ + y] = acc;
}

// ---------------------------------------------------------------- launch
extern "C" void kernel_launch(void* const* d_in, const int* in_sizes, int n_in,
                              void* d_out, int out_size, void* d_ws, size_t ws_size,
                              hipStream_t stream) {
    const int*   x       = (const int*)d_in[0];
    const float* embed_w = (const float*)d_in[2];
    const float* conv_w  = (const float*)d_in[3];
    const float* conv_b  = (const float*)d_in[4];
    const float* U4_w    = (const float*)d_in[5];
    const float* gcn_w   = (const float*)d_in[6];
    const float* gcn_b   = (const float*)d_in[7];
    const float* adj     = (const float*)d_in[8];
    const float* f4t_w   = (const float*)d_in[9];
    const float* f4t_b   = (const float*)d_in[10];
    const float* f4_w    = (const float*)d_in[11];
    const float* f4_b    = (const float*)d_in[12];
    float* out = (float*)d_out;

    char* ws = (char*)d_ws;
    const size_t SZ_WT  = 180224;                            // 9*50*100*4 rounded
    const size_t SZ_HP  = (size_t)B_ * LP * 64 * 2;          // 2,588,672
    const size_t SZ_BT  = (size_t)KT_ * NT_ * 32 * 2;        // 7,454,720
    const size_t SZ_M4T = (size_t)B_ * Y_ * F_ * 4;          // 14,275,200
    int*   flag = (int*)ws;
    float* wT   = (float*)(ws + 16);
    u16*   hp   = (u16*)(ws + 16 + SZ_WT);
    u16*   hpT  = (u16*)(ws + 16 + SZ_WT + SZ_HP);
    u16*   Bt   = (u16*)(ws + 16 + SZ_WT + 2 * SZ_HP);
    float* m4t  = (float*)(ws + 16 + SZ_WT + 2 * SZ_HP + SZ_BT);
    float* outp = (float*)(ws + 16 + SZ_WT + 2 * SZ_HP + SZ_BT + SZ_M4T);  // KP_*Y*400*4 = 57 MB

    k0_prep<<<9, 256, 0, stream>>>(x, conv_w, flag, wT);
    k1_conv<<<dim3(40, 8), 256, 0, stream>>>(x, flag, embed_w, wT, conv_b, hp, hpT);
    hipMemsetAsync(Bt, 0, SZ_BT, stream);
    k2_attn<<<dim3(70, 8), 256, 0, stream>>>(U4_w, hp, hpT, m4t);
    k3_support<<<dim3(35, 8), 256, 0, stream>>>(m4t, gcn_w, f4t_w, f4t_b, Bt, out);
    k4_gemm<<<dim3(140 * KP_), 256, 0, stream>>>(adj, Bt, outp);
    k5_final<<<dim3(35, 8), 256, 0, stream>>>(outp, m4t, gcn_b, f4_w, f4_b,
                                              out + (size_t)B_ * Y_);
}

// Round 5
// 927.276 us; speedup vs baseline: 1.0465x; 1.0465x over previous
//
#include <hip/hip_runtime.h>

typedef unsigned short u16;
typedef short bf16x8 __attribute__((ext_vector_type(8)));   // MFMA A/B frag (8 bf16)
typedef float f32x4  __attribute__((ext_vector_type(4)));   // MFMA C/D frag
typedef u16   u16x8  __attribute__((ext_vector_type(8)));   // 16B vector ld/st

#define MFMA_BF16(a, b, c) __builtin_amdgcn_mfma_f32_16x16x32_bf16((a), (b), (c), 0, 0, 0)

#define B_  8
#define L_  2500
#define LP  2528          // L padded to 79*32
#define E_  100
#define F_  50
#define Y_  8922
#define YP  8960          // Y padded to 280*32
#define KT_ 280           // K tiles of 32 over YP
#define NT_ 416           // N = B*F = 400 padded to 26*16
#define KP_ 3             // K-split: parts of 94/93/93 tiles; grid 420 <= 512
                          // co-residency capacity at 2 blocks/CU -> ONE dispatch
                          // wave (KP_=4's 560 blocks ran as 512+48 = 2 waves,
                          // doubling k4 makespan; R2/R4 counters fit that model)
#define AMAX_ (Y_ * Y_ - 1)

__device__ __forceinline__ u16 f2bf(float f) {
    unsigned int x = __float_as_uint(f);
    unsigned int r = x + 0x7fffu + ((x >> 16) & 1u);   // RNE
    return (u16)(r >> 16);
}

// direct global->LDS copies (wave-uniform LDS base + lane*size, per-lane global src)
__device__ __forceinline__ void glds16(const void* g, const void* l) {
    __builtin_amdgcn_global_load_lds(
        (const __attribute__((address_space(1))) unsigned int*)(unsigned long long)g,
        (__attribute__((address_space(3))) unsigned int*)(unsigned int)(unsigned long long)l,
        16, 0, 0);
}
__device__ __forceinline__ void glds4(const void* g, const void* l) {
    __builtin_amdgcn_global_load_lds(
        (const __attribute__((address_space(1))) unsigned int*)(unsigned long long)g,
        (__attribute__((address_space(3))) unsigned int*)(unsigned int)(unsigned long long)l,
        4, 0, 0);
}

// ---------------------------------------------------------------- prep
__global__ __launch_bounds__(256) void k0_prep(
    const int* __restrict__ x, const float* __restrict__ conv_w,
    int* __restrict__ flag, float* __restrict__ wT)
{
    const int k = blockIdx.x;           // 0..8
    const int tid = threadIdx.x;
    if (k == 0 && tid == 0) {
        int nz = 0;
        #pragma unroll
        for (int i = 0; i < 32; i++) nz |= x[2 * i + 1];
        *flag = (nz == 0) ? 1 : 0;      // all-high-words-zero => int64 buffer
    }
    for (int j = tid; j < 5000; j += 256)           // j = f*100 + e
        wT[k * 5000 + j] = conv_w[j * 9 + k];
}

// ---------------------------------------------------------------- conv (fp32, LDS-staged weights)
__global__ __launch_bounds__(256) void k1_conv(
    const int* __restrict__ x, const int* __restrict__ flag,
    const float* __restrict__ embed_w, const float* __restrict__ wT,
    const float* __restrict__ conv_b,
    u16* __restrict__ hp, u16* __restrict__ hpT)
{
    __shared__ float sEmb[72 * 104];   // 72 rows (64 + 8 halo), stride 104
    __shared__ float sW[50 * 104];     // per-k weight slice [f][e], stride 104
    __shared__ int   sId[72];
    const int tid = threadIdx.x;
    const int b  = blockIdx.y;
    const int l0 = blockIdx.x * 64;
    const int is64 = *flag;

    if (tid < 72) {
        int l = l0 - 4 + tid;
        int id = -1;
        if (l >= 0 && l < L_) id = is64 ? x[(b * L_ + l) * 2] : x[b * L_ + l];
        sId[tid] = id;
    }
    __syncthreads();
    for (int i = tid; i < 72 * 25; i += 256) {       // float4 granules
        int r = i / 25, e4 = i - r * 25;
        int id = sId[r];
        float4 v = make_float4(0.f, 0.f, 0.f, 0.f);
        if (id >= 0) v = *(const float4*)&embed_w[(size_t)id * 100 + e4 * 4];
        *(float4*)&sEmb[r * 104 + e4 * 4] = v;
    }

    const int li = tid & 63;
    const int fg = __builtin_amdgcn_readfirstlane(tid >> 6);   // wave-uniform f-group 0..3

    float acc[13];
    #pragma unroll
    for (int i = 0; i < 13; i++) { int f = fg + 4 * i; acc[i] = (f < F_) ? conv_b[f] : 0.f; }

    for (int k = 0; k < 9; k++) {
        __syncthreads();
        for (int i = tid; i < 1250; i += 256) {      // stage wT[k] : 50 f x 25 float4
            int f = i / 25, e4 = i - f * 25;
            *(float4*)&sW[f * 104 + e4 * 4] = *(const float4*)&wT[k * 5000 + f * 100 + e4 * 4];
        }
        __syncthreads();
        for (int e4 = 0; e4 < 25; e4++) {
            float4 h = *(const float4*)&sEmb[(li + k) * 104 + e4 * 4];
            #pragma unroll
            for (int i = 0; i < 13; i++) {
                int f = fg + 4 * i;
                if (f < F_) {
                    float4 w = *(const float4*)&sW[f * 104 + e4 * 4];   // uniform -> LDS broadcast
                    acc[i] += h.x * w.x + h.y * w.y + h.z * w.z + h.w * w.w;
                }
            }
        }
    }

    int l = l0 + li;
    if (l < LP) {
        bool valid = (l < L_);
        #pragma unroll
        for (int i = 0; i < 13; i++) {
            int f = fg + 4 * i;
            if (f < F_) {
                u16 hv = 0;
                if (valid) {
                    float e2 = __expf(2.f * acc[i]);
                    hv = f2bf((e2 - 1.f) / (e2 + 1.f));   // tanh
                }
                hp [((size_t)b * LP + l) * 64 + f] = hv;
                hpT[((size_t)b * 64 + f) * LP + l] = hv;
            }
        }
        #pragma unroll
        for (int j = 0; j < 4; j++) {
            int f = 50 + fg + 4 * j;
            if (f < 64) {
                hp [((size_t)b * LP + l) * 64 + f] = 0;
                hpT[((size_t)b * 64 + f) * LP + l] = (f == 50 && valid) ? f2bf(1.f) : (u16)0;
            }
        }
    }
}

// ---------------------------------------------------------------- flash attention (reg-prefetch pipelined)
__global__ __launch_bounds__(256) void k2_attn(
    const float* __restrict__ U4_w,
    const u16* __restrict__ hp, const u16* __restrict__ hpT,
    float* __restrict__ m4t)
{
    __shared__ u16  sU4[128 * 72];   // [y][f] f-contig, rows padded 72
    __shared__ u16  sHp[32 * 72];    // [l][f] f-contig (S-GEMM B)
    __shared__ u16  sHt[64 * 40];    // [f][l] l-contig (PV B), rows padded 40
    __shared__ u16  sP [128 * 40];   // [y][l] l-contig (PV A)
    __shared__ float sDen[128];

    const int tid  = threadIdx.x;
    const int b    = blockIdx.y;
    const int y0   = blockIdx.x * 128;
    const int w    = tid >> 6;
    const int lane = tid & 63;
    const int l15  = lane & 15;
    const int quad = lane >> 4;

    for (int i = tid; i < 128 * 72; i += 256) {
        int r = i / 72, c = i - r * 72;
        float v = 0.f;
        int y = y0 + r;
        if (c < F_ && y < Y_) v = U4_w[y * F_ + c];
        sU4[i] = f2bf(v);
    }
    __syncthreads();

    bf16x8 fa[2][2];   // hoisted U4 A-frags
    #pragma unroll
    for (int mi = 0; mi < 2; mi++)
        #pragma unroll
        for (int ks = 0; ks < 2; ks++)
            fa[mi][ks] = *(const bf16x8*)&sU4[(w * 32 + mi * 16 + l15) * 72 + ks * 32 + quad * 8];

    const f32x4 fz = {0.f, 0.f, 0.f, 0.f};
    f32x4 pacc[2][4];
    #pragma unroll
    for (int mi = 0; mi < 2; mi++)
        #pragma unroll
        for (int ni = 0; ni < 4; ni++) pacc[mi][ni] = fz;

    // staging coords + prefetch regs
    const int rr = tid >> 3, seg = tid & 7;      // hp tile [32][64]
    const int fr = tid >> 2, s2 = tid & 3;       // hpT tile [64][32]
    u16x8 pv, pv2;
    {
        pv  = *(const u16x8*)&hp [((size_t)b * LP + rr) * 64 + seg * 8];
        pv2 = *(const u16x8*)&hpT[((size_t)b * 64 + fr) * LP + s2 * 8];
    }

    for (int lt = 0; lt < 79; lt++) {
        const int l0 = lt * 32;
        __syncthreads();
        *(u16x8*)&sHp[rr * 72 + seg * 8] = pv;
        *(u16x8*)&sHt[fr * 40 + s2 * 8] = pv2;
        if (lt + 1 < 79) {   // prefetch next tile; latency hidden under S+PV compute
            const int ln = l0 + 32;
            pv  = *(const u16x8*)&hp [((size_t)b * LP + ln + rr) * 64 + seg * 8];
            pv2 = *(const u16x8*)&hpT[((size_t)b * 64 + fr) * LP + ln + s2 * 8];
        }
        __syncthreads();

        // S = U4p [y×64f] · hp^T [64f×l]
        f32x4 sacc[2][2];
        #pragma unroll
        for (int mi = 0; mi < 2; mi++)
            #pragma unroll
            for (int ni = 0; ni < 2; ni++) sacc[mi][ni] = fz;
        #pragma unroll
        for (int ks = 0; ks < 2; ks++) {
            #pragma unroll
            for (int ni = 0; ni < 2; ni++) {
                bf16x8 fb = *(const bf16x8*)&sHp[(ni * 16 + l15) * 72 + ks * 32 + quad * 8];
                #pragma unroll
                for (int mi = 0; mi < 2; mi++)
                    sacc[mi][ni] = MFMA_BF16(fa[mi][ks], fb, sacc[mi][ni]);
            }
        }
        // P = exp(S), write to LDS in A-layout
        #pragma unroll
        for (int mi = 0; mi < 2; mi++)
            #pragma unroll
            for (int ni = 0; ni < 2; ni++) {
                int lcol = ni * 16 + l15;
                bool lv = (l0 + lcol) < L_;
                #pragma unroll
                for (int r = 0; r < 4; r++) {
                    float p = lv ? __expf(sacc[mi][ni][r]) : 0.f;
                    sP[(w * 32 + mi * 16 + quad * 4 + r) * 40 + lcol] = f2bf(p);
                }
            }
        __syncthreads();

        // O += P [y×32l] · hp [32l×64f]
        bf16x8 fv[4];
        #pragma unroll
        for (int ni = 0; ni < 4; ni++)
            fv[ni] = *(const bf16x8*)&sHt[(ni * 16 + l15) * 40 + quad * 8];
        #pragma unroll
        for (int mi = 0; mi < 2; mi++) {
            bf16x8 fp_ = *(const bf16x8*)&sP[(w * 32 + mi * 16 + l15) * 40 + quad * 8];
            #pragma unroll
            for (int ni = 0; ni < 4; ni++)
                pacc[mi][ni] = MFMA_BF16(fp_, fv[ni], pacc[mi][ni]);
        }
    }

    // denominator column: f=50 -> ni=3, lane&15==2
    if (l15 == 2) {
        #pragma unroll
        for (int mi = 0; mi < 2; mi++)
            #pragma unroll
            for (int r = 0; r < 4; r++)
                sDen[w * 32 + mi * 16 + quad * 4 + r] = pacc[mi][3][r];
    }
    __syncthreads();

    #pragma unroll
    for (int mi = 0; mi < 2; mi++)
        #pragma unroll
        for (int ni = 0; ni < 4; ni++) {
            int f = ni * 16 + l15;
            if (f < F_) {
                #pragma unroll
                for (int r = 0; r < 4; r++) {
                    int yl = w * 32 + mi * 16 + quad * 4 + r;
                    int y = y0 + yl;
                    if (y < Y_)
                        m4t[((size_t)b * Y_ + y) * F_ + f] = pacc[mi][ni][r] / sDen[yl];
                }
            }
        }
}

// ---------------------------------------------------------------- support + y4t
// Bt tile image (per kt): u16[416*32], PRE-SWIZZLED so that k4's linear
// global_load_lds image gives conflict-free ds_read_b128:
//   image[n*32 + ((z>>3) ^ ((n>>1)&3))*8 + (z&7)] = bf16(support[n][z])
__global__ __launch_bounds__(256) void k3_support(
    const float* __restrict__ m4t, const float* __restrict__ gcn_w,
    const float* __restrict__ f4t_w, const float* __restrict__ f4t_b,
    u16* __restrict__ Bt, float* __restrict__ y4t_out)
{
    __shared__ float sW[50 * 52];   // gcn_w^T : [g][f], rows padded 52
    const int tid = threadIdx.x;
    for (int i = tid; i < 50 * 52; i += 256) {
        int g = i / 52, f = i - g * 52;
        sW[i] = (f < F_) ? gcn_w[f * F_ + g] : 0.f;
    }
    __syncthreads();

    const int b = blockIdx.y;
    const int y = blockIdx.x * 256 + tid;
    if (y >= Y_) return;

    float2 m[25];
    const float* mrow = m4t + ((size_t)b * Y_ + y) * F_;
    #pragma unroll
    for (int i = 0; i < 25; i++) m[i] = *(const float2*)(mrow + 2 * i);

    const int kt = y >> 5, zo = y & 31;
    const int zhi = zo >> 3, zlo = zo & 7;
    u16* btile = Bt + (size_t)kt * (NT_ * 32);
    for (int g = 0; g < F_; g++) {
        float s = 0.f;
        const float* wr = sW + g * 52;
        #pragma unroll
        for (int i = 0; i < 25; i++) {
            float2 wv = *(const float2*)(wr + 2 * i);
            s += m[i].x * wv.x + m[i].y * wv.y;
        }
        int n = b * F_ + g;
        btile[n * 32 + ((zhi ^ ((n >> 1) & 3)) << 3) + zlo] = f2bf(s);
    }

    const float* tw = f4t_w + (size_t)y * F_;
    float acc = f4t_b[y];
    #pragma unroll
    for (int i = 0; i < 25; i++) {
        float2 wv = *(const float2*)(tw + 2 * i);
        acc += m[i].x * wv.x + m[i].y * wv.y;
    }
    y4t_out[(size_t)b * Y_ + y] = acc;
}

// ---------------------------------------------------------------- adj GEMM
// Asymmetric-depth counted-vmcnt pipeline (unchanged from R4):
//   A (adj, HBM stream): 3 buffers -> staged 2 tiles ahead
//   B (Bt, L2/L3-resident): 2 buffers -> staged 1 tile ahead
// Per iter: issue B(t+1)[8] + A(t+2)[8]; single s_waitcnt vmcnt(24) proves
// B(t),A(t) landed (in-order retirement, m135); no vmcnt(0) in the loop.
// KP_=3 -> grid 420 <= 512-block co-residency (2 blocks/CU at 76KB LDS):
// ONE dispatch wave. R2/R4's KP_=4 grid of 560 ran as 512+48 (two waves),
// doubling makespan (counters: MfmaUtil 13% = 26%/2, Occupancy 15.7%).
__global__ __launch_bounds__(256, 2) void k4_gemm(
    const float* __restrict__ adj, const u16* __restrict__ Bt,
    float* __restrict__ outp)
{
    __shared__ float sA[3][64 * 32];    // fp32 A-tiles (swizzled image), 3x8 KB
    __shared__ u16   sB[2][NT_ * 32];   // bf16 B-tiles (pre-swizzled image), 2x26 KB

    const int tid  = threadIdx.x;
    const int bid  = blockIdx.x;
    const int kp   = bid % KP_;                     // 0..2
    const int mIdx = bid / KP_;                     // 0..139
    const int m0   = mIdx * 64;
    const int w    = tid >> 6;
    const int wq   = __builtin_amdgcn_readfirstlane(w);
    const int lane = tid & 63;
    const int l15  = lane & 15;
    const int quad = lane >> 4;
    const int wm   = w & 1;        // M sub-block (0..1) -> rows wm*32..+32
    const int wn   = w >> 1;       // N half (0..1) -> cols wn*208..+208

    // A staging: round j, thread t fills physical word j*256+t = (row, cphys).
    // logical col = ((cphys>>2) ^ (row&7))*4 + (cphys&3); row&7 == tid>>5 for all rounds.
    const int rA   = tid >> 5;                                       // 0..7
    const int colA = ((((tid & 31) >> 2) ^ rA) << 2) | (tid & 3);    // 0..31, round-invariant
    const unsigned rbaseA = (unsigned)(m0 + rA) * (unsigned)Y_ + (unsigned)colA;

    // lane-const swizzled read offsets
    const int r7    = l15 & 7;
    const int offA0 = (((2 * quad)     ^ r7) << 2);   // float offset of 1st 16B slot
    const int offA1 = (((2 * quad + 1) ^ r7) << 2);   // float offset of 2nd 16B slot
    const int offB  = ((quad ^ ((l15 >> 1) & 3)) << 3); // u16 offset of B slot

    const f32x4 fz = {0.f, 0.f, 0.f, 0.f};
    f32x4 acc[2][13];
    #pragma unroll
    for (int mi = 0; mi < 2; mi++)
        #pragma unroll
        for (int ni = 0; ni < 13; ni++) acc[mi][ni] = fz;

    // B stage = 8 loads/thread (6x glds16 + 2x glds4); A stage = 8 loads/thread (glds4)
    auto stageB = [&](int buf, int kt) {
        const char* bt = (const char*)Bt + (size_t)kt * (NT_ * 32 * 2);
        char* sb = (char*)sB[buf];
        #pragma unroll
        for (int j = 0; j < 6; j++)
            glds16(bt + j * 4096 + tid * 16, sb + j * 4096 + wq * 1024);
        #pragma unroll
        for (int j = 0; j < 2; j++)
            glds4(bt + 24576 + j * 1024 + tid * 4, sb + 24576 + j * 1024 + wq * 256);
    };
    auto stageA = [&](int buf, int kt) {
        char* sa = (char*)sA[buf];
        const unsigned idx0 = rbaseA + (unsigned)kt * 32u;
        #pragma unroll
        for (int j = 0; j < 8; j++) {
            unsigned idx = idx0 + (unsigned)(j * 8 * Y_);
            idx = (idx > (unsigned)AMAX_) ? (unsigned)AMAX_ : idx;   // OOB clamp (harmless rows/cols)
            glds4(adj + idx, sa + j * 1024 + wq * 256);
        }
    };

    // K-split: kp0 = [0,94) (94 tiles), kp1 = [94,187), kp2 = [187,280) (93 each)
    const int kt0   = (kp == 0) ? 0 : 1 + 93 * kp;
    const int niter = 93 + (kp == 0);
    const int ktmax = kt0 + niter - 1;
    // prologue issue order (vmcnt accounting depends on it): B0[8], A0[8], A1[8]
    stageB(0, kt0);
    stageA(0, kt0);
    stageA(1, kt0 + 1);

    int a0 = 0;   // A buffer index = t % 3
    for (int it = 0; it < niter; it++) {
        int ktb = kt0 + it + 1; if (ktb > ktmax) ktb = ktmax;
        int kta = kt0 + it + 2; if (kta > ktmax) kta = ktmax;
        stageB((it + 1) & 1, ktb);
        int a2 = a0 + 2; if (a2 >= 3) a2 -= 3;
        stageA(a2, kta);
        asm volatile("s_waitcnt vmcnt(24)" ::: "memory");   // B(t), A(t) landed
        __builtin_amdgcn_s_barrier();            // raw: no compiler drain
        __builtin_amdgcn_sched_barrier(0);

        const float* sAc = sA[a0];
        const u16*   sBc = sB[it & 1];
        bf16x8 fa[2];
        #pragma unroll
        for (int mi = 0; mi < 2; mi++) {
            const int rb = (wm * 32 + mi * 16 + l15) * 32;
            f32x4 x0 = *(const f32x4*)&sAc[rb + offA0];
            f32x4 x1 = *(const f32x4*)&sAc[rb + offA1];
            bf16x8 v;
            v[0] = (short)f2bf(x0[0]); v[1] = (short)f2bf(x0[1]);
            v[2] = (short)f2bf(x0[2]); v[3] = (short)f2bf(x0[3]);
            v[4] = (short)f2bf(x1[0]); v[5] = (short)f2bf(x1[1]);
            v[6] = (short)f2bf(x1[2]); v[7] = (short)f2bf(x1[3]);
            fa[mi] = v;
        }
        #pragma unroll
        for (int ni = 0; ni < 13; ni++) {
            bf16x8 fb = *(const bf16x8*)&sBc[(wn * 208 + ni * 16 + l15) * 32 + offB];
            acc[0][ni] = MFMA_BF16(fa[0], fb, acc[0][ni]);
            acc[1][ni] = MFMA_BF16(fa[1], fb, acc[1][ni]);
        }

        __builtin_amdgcn_sched_barrier(0);
        asm volatile("s_waitcnt lgkmcnt(0)" ::: "memory");   // reads of this tile done
        __builtin_amdgcn_s_barrier();            // raw: buffers free for overwrite
        __builtin_amdgcn_sched_barrier(0);       // pin next-iter glds below the barrier
        a0++; if (a0 >= 3) a0 = 0;
    }
    asm volatile("s_waitcnt vmcnt(0)" ::: "memory");   // drain dummy in-flight loads
    __builtin_amdgcn_sched_barrier(0);

    float* dst = outp + (size_t)kp * Y_ * 400;
    #pragma unroll
    for (int mi = 0; mi < 2; mi++)
        #pragma unroll
        for (int ni = 0; ni < 13; ni++) {
            int n = wn * 208 + ni * 16 + l15;
            if (n < 400) {
                #pragma unroll
                for (int r4 = 0; r4 < 4; r4++) {
                    int y = m0 + wm * 32 + mi * 16 + quad * 4 + r4;
                    if (y < Y_) dst[(size_t)y * 400 + n] = acc[mi][ni][r4];
                }
            }
        }
}

// ---------------------------------------------------------------- final y4
__global__ __launch_bounds__(256) void k5_final(
    const float* __restrict__ outp, const float* __restrict__ m4t,
    const float* __restrict__ gcn_b, const float* __restrict__ f4_w,
    const float* __restrict__ f4_b, float* __restrict__ y4_out)
{
    const int b = blockIdx.y;
    const int y = blockIdx.x * 256 + threadIdx.x;
    if (y >= Y_) return;

    const size_t PS = (size_t)Y_ * 400;
    const float* p0 = outp + (size_t)y * 400 + b * F_;
    const float* fw = f4_w + (size_t)y * 100;
    const float* mrow = m4t + ((size_t)b * Y_ + y) * F_;

    float acc = f4_b[y];
    #pragma unroll
    for (int i = 0; i < 25; i++) {
        float2 mv = *(const float2*)(mrow + 2 * i);
        float2 wv = *(const float2*)(fw + 2 * i);
        acc += mv.x * wv.x + mv.y * wv.y;
    }
    #pragma unroll
    for (int i = 0; i < 25; i++) {
        float sx = 0.f, sy = 0.f;
        #pragma unroll
        for (int kp = 0; kp < KP_; kp++) {
            float2 v = *(const float2*)(p0 + kp * PS + 2 * i);
            sx += v.x; sy += v.y;
        }
        float2 gb = *(const float2*)(gcn_b + 2 * i);
        sx += gb.x; sy += gb.y;
        sx = sx > 0.f ? sx : 0.2f * sx;   // leaky_relu
        sy = sy > 0.f ? sy : 0.2f * sy;
        float2 wv = *(const float2*)(fw + 50 + 2 * i);
        acc += sx * wv.x + sy * wv.y;
    }
    y4_out[(size_t)b * Y_ + y] = acc;
}

// ---------------------------------------------------------------- launch
extern "C" void kernel_launch(void* const* d_in, const int* in_sizes, int n_in,
                              void* d_out, int out_size, void* d_ws, size_t ws_size,
                              hipStream_t stream) {
    const int*   x       = (const int*)d_in[0];
    const float* embed_w = (const float*)d_in[2];
    const float* conv_w  = (const float*)d_in[3];
    const float* conv_b  = (const float*)d_in[4];
    const float* U4_w    = (const float*)d_in[5];
    const float* gcn_w   = (const float*)d_in[6];
    const float* gcn_b   = (const float*)d_in[7];
    const float* adj     = (const float*)d_in[8];
    const float* f4t_w   = (const float*)d_in[9];
    const float* f4t_b   = (const float*)d_in[10];
    const float* f4_w    = (const float*)d_in[11];
    const float* f4_b    = (const float*)d_in[12];
    float* out = (float*)d_out;

    char* ws = (char*)d_ws;
    const size_t SZ_WT  = 180224;                            // 9*50*100*4 rounded
    const size_t SZ_HP  = (size_t)B_ * LP * 64 * 2;          // 2,588,672
    const size_t SZ_BT  = (size_t)KT_ * NT_ * 32 * 2;        // 7,454,720
    const size_t SZ_M4T = (size_t)B_ * Y_ * F_ * 4;          // 14,275,200
    int*   flag = (int*)ws;
    float* wT   = (float*)(ws + 16);
    u16*   hp   = (u16*)(ws + 16 + SZ_WT);
    u16*   hpT  = (u16*)(ws + 16 + SZ_WT + SZ_HP);
    u16*   Bt   = (u16*)(ws + 16 + SZ_WT + 2 * SZ_HP);
    float* m4t  = (float*)(ws + 16 + SZ_WT + 2 * SZ_HP + SZ_BT);
    float* outp = (float*)(ws + 16 + SZ_WT + 2 * SZ_HP + SZ_BT + SZ_M4T);  // KP_*Y*400*4 = 43 MB

    k0_prep<<<9, 256, 0, stream>>>(x, conv_w, flag, wT);
    k1_conv<<<dim3(40, 8), 256, 0, stream>>>(x, flag, embed_w, wT, conv_b, hp, hpT);
    hipMemsetAsync(Bt, 0, SZ_BT, stream);
    k2_attn<<<dim3(70, 8), 256, 0, stream>>>(U4_w, hp, hpT, m4t);
    k3_support<<<dim3(35, 8), 256, 0, stream>>>(m4t, gcn_w, f4t_w, f4t_b, Bt, out);
    k4_gemm<<<dim3(140 * KP_), 256, 0, stream>>>(adj, Bt, outp);
    k5_final<<<dim3(35, 8), 256, 0, stream>>>(outp, m4t, gcn_b, f4_w, f4_b,
                                              out + (size_t)B_ * Y_);
}

// Round 6
// 866.503 us; speedup vs baseline: 1.1199x; 1.0701x over previous
//
#include <hip/hip_runtime.h>

typedef unsigned short u16;
typedef short bf16x8 __attribute__((ext_vector_type(8)));   // MFMA A/B frag (8 bf16)
typedef float f32x4  __attribute__((ext_vector_type(4)));   // MFMA C/D frag
typedef u16   u16x8  __attribute__((ext_vector_type(8)));   // 16B vector ld/st

#define MFMA_BF16(a, b, c) __builtin_amdgcn_mfma_f32_16x16x32_bf16((a), (b), (c), 0, 0, 0)

#define B_  8
#define L_  2500
#define LP  2528          // L padded to 79*32
#define E_  100
#define F_  50
#define Y_  8922
#define YP  8960          // Y padded to 280*32
#define KT_ 280           // K tiles of 32 over YP
#define NT_ 416           // N = B*F = 400 padded to 26*16
#define KP_ 3             // K-split: parts of 94/93/93 tiles; grid 420 <= 512
#define AMAX_ (Y_ * Y_ - 1)

__device__ __forceinline__ u16 f2bf(float f) {
    unsigned int x = __float_as_uint(f);
    unsigned int r = x + 0x7fffu + ((x >> 16) & 1u);   // RNE
    return (u16)(r >> 16);
}

// direct global->LDS copies (wave-uniform LDS base + lane*size, per-lane global src)
__device__ __forceinline__ void glds16(const void* g, const void* l) {
    __builtin_amdgcn_global_load_lds(
        (const __attribute__((address_space(1))) unsigned int*)(unsigned long long)g,
        (__attribute__((address_space(3))) unsigned int*)(unsigned int)(unsigned long long)l,
        16, 0, 0);
}
__device__ __forceinline__ void glds4(const void* g, const void* l) {
    __builtin_amdgcn_global_load_lds(
        (const __attribute__((address_space(1))) unsigned int*)(unsigned long long)g,
        (__attribute__((address_space(3))) unsigned int*)(unsigned int)(unsigned long long)l,
        4, 0, 0);
}

// ---------------------------------------------------------------- prep
__global__ __launch_bounds__(256) void k0_prep(
    const int* __restrict__ x, const float* __restrict__ conv_w,
    int* __restrict__ flag, float* __restrict__ wT)
{
    const int k = blockIdx.x;           // 0..8
    const int tid = threadIdx.x;
    if (k == 0 && tid == 0) {
        int nz = 0;
        #pragma unroll
        for (int i = 0; i < 32; i++) nz |= x[2 * i + 1];
        *flag = (nz == 0) ? 1 : 0;      // all-high-words-zero => int64 buffer
    }
    for (int j = tid; j < 5000; j += 256)           // j = f*100 + e
        wT[k * 5000 + j] = conv_w[j * 9 + k];
}

// ---------------------------------------------------------------- conv (fp32)
// R5 rework: k1 was LDS-LATENCY bound (190us, VALUBusy 24%, ~1.2 waves/SIMD:
// serial dependent w-loads from LDS, ~120cy each, no TLP to hide them).
//  - w reads go straight to L2-resident wT via wave-uniform addresses
//    (fg is readfirstlane-uniform -> s_load path); sW staging + 18 barriers gone
//  - 13 loads batched per e4 via full unroll + clamped uniform index
//  - sEmb stride 108 floats (27 16B-slots, odd) -> h-reads conflict-free
__global__ __launch_bounds__(256) void k1_conv(
    const int* __restrict__ x, const int* __restrict__ flag,
    const float* __restrict__ embed_w, const float* __restrict__ wT,
    const float* __restrict__ conv_b,
    u16* __restrict__ hp, u16* __restrict__ hpT)
{
    __shared__ float sEmb[72 * 108];   // 72 rows (64 + 8 halo), stride 108
    __shared__ int   sId[72];
    const int tid = threadIdx.x;
    const int b  = blockIdx.y;
    const int l0 = blockIdx.x * 64;
    const int is64 = *flag;

    if (tid < 72) {
        int l = l0 - 4 + tid;
        int id = -1;
        if (l >= 0 && l < L_) id = is64 ? x[(b * L_ + l) * 2] : x[b * L_ + l];
        sId[tid] = id;
    }
    __syncthreads();
    for (int i = tid; i < 72 * 25; i += 256) {       // float4 granules
        int r = i / 25, e4 = i - r * 25;
        int id = sId[r];
        float4 v = make_float4(0.f, 0.f, 0.f, 0.f);
        if (id >= 0) v = *(const float4*)&embed_w[(size_t)id * 100 + e4 * 4];
        *(float4*)&sEmb[r * 108 + e4 * 4] = v;
    }
    __syncthreads();

    const int li = tid & 63;
    const int fg = __builtin_amdgcn_readfirstlane(tid >> 6);   // wave-uniform f-group 0..3

    int fidx[13];     // clamped f per slot (uniform); duplicate f=49 compute for
    #pragma unroll    // fg>=2 slot 12 is discarded by the f<F_ store guard
    for (int i = 0; i < 13; i++) { int f = fg + 4 * i; fidx[i] = (f < F_) ? f : 49; }

    float acc[13];
    #pragma unroll
    for (int i = 0; i < 13; i++) { int f = fg + 4 * i; acc[i] = (f < F_) ? conv_b[f] : 0.f; }

    for (int k = 0; k < 9; k++) {
        const float* wk = wT + k * 5000;
        for (int e4 = 0; e4 < 25; e4++) {
            float4 h = *(const float4*)&sEmb[(li + k) * 108 + e4 * 4];
            #pragma unroll
            for (int i = 0; i < 13; i++) {     // 13 independent uniform loads batch
                float4 w = *(const float4*)&wk[fidx[i] * 100 + e4 * 4];
                acc[i] += h.x * w.x + h.y * w.y + h.z * w.z + h.w * w.w;
            }
        }
    }

    int l = l0 + li;
    if (l < LP) {
        bool valid = (l < L_);
        #pragma unroll
        for (int i = 0; i < 13; i++) {
            int f = fg + 4 * i;
            if (f < F_) {
                u16 hv = 0;
                if (valid) {
                    float e2 = __expf(2.f * acc[i]);
                    hv = f2bf((e2 - 1.f) / (e2 + 1.f));   // tanh
                }
                hp [((size_t)b * LP + l) * 64 + f] = hv;
                hpT[((size_t)b * 64 + f) * LP + l] = hv;
            }
        }
        #pragma unroll
        for (int j = 0; j < 4; j++) {
            int f = 50 + fg + 4 * j;
            if (f < 64) {
                hp [((size_t)b * LP + l) * 64 + f] = 0;
                hpT[((size_t)b * 64 + f) * LP + l] = (f == 50 && valid) ? f2bf(1.f) : (u16)0;
            }
        }
    }
}

// ---------------------------------------------------------------- flash attention (reg-prefetch pipelined)
__global__ __launch_bounds__(256) void k2_attn(
    const float* __restrict__ U4_w,
    const u16* __restrict__ hp, const u16* __restrict__ hpT,
    float* __restrict__ m4t)
{
    __shared__ u16  sU4[128 * 72];   // [y][f] f-contig, rows padded 72
    __shared__ u16  sHp[32 * 72];    // [l][f] f-contig (S-GEMM B)
    __shared__ u16  sHt[64 * 40];    // [f][l] l-contig (PV B), rows padded 40
    __shared__ u16  sP [128 * 40];   // [y][l] l-contig (PV A)
    __shared__ float sDen[128];

    const int tid  = threadIdx.x;
    const int b    = blockIdx.y;
    const int y0   = blockIdx.x * 128;
    const int w    = tid >> 6;
    const int lane = tid & 63;
    const int l15  = lane & 15;
    const int quad = lane >> 4;

    for (int i = tid; i < 128 * 72; i += 256) {
        int r = i / 72, c = i - r * 72;
        float v = 0.f;
        int y = y0 + r;
        if (c < F_ && y < Y_) v = U4_w[y * F_ + c];
        sU4[i] = f2bf(v);
    }
    __syncthreads();

    bf16x8 fa[2][2];   // hoisted U4 A-frags
    #pragma unroll
    for (int mi = 0; mi < 2; mi++)
        #pragma unroll
        for (int ks = 0; ks < 2; ks++)
            fa[mi][ks] = *(const bf16x8*)&sU4[(w * 32 + mi * 16 + l15) * 72 + ks * 32 + quad * 8];

    const f32x4 fz = {0.f, 0.f, 0.f, 0.f};
    f32x4 pacc[2][4];
    #pragma unroll
    for (int mi = 0; mi < 2; mi++)
        #pragma unroll
        for (int ni = 0; ni < 4; ni++) pacc[mi][ni] = fz;

    // staging coords + prefetch regs
    const int rr = tid >> 3, seg = tid & 7;      // hp tile [32][64]
    const int fr = tid >> 2, s2 = tid & 3;       // hpT tile [64][32]
    u16x8 pv, pv2;
    {
        pv  = *(const u16x8*)&hp [((size_t)b * LP + rr) * 64 + seg * 8];
        pv2 = *(const u16x8*)&hpT[((size_t)b * 64 + fr) * LP + s2 * 8];
    }

    for (int lt = 0; lt < 79; lt++) {
        const int l0 = lt * 32;
        __syncthreads();
        *(u16x8*)&sHp[rr * 72 + seg * 8] = pv;
        *(u16x8*)&sHt[fr * 40 + s2 * 8] = pv2;
        if (lt + 1 < 79) {   // prefetch next tile; latency hidden under S+PV compute
            const int ln = l0 + 32;
            pv  = *(const u16x8*)&hp [((size_t)b * LP + ln + rr) * 64 + seg * 8];
            pv2 = *(const u16x8*)&hpT[((size_t)b * 64 + fr) * LP + ln + s2 * 8];
        }
        __syncthreads();

        // S = U4p [y×64f] · hp^T [64f×l]
        f32x4 sacc[2][2];
        #pragma unroll
        for (int mi = 0; mi < 2; mi++)
            #pragma unroll
            for (int ni = 0; ni < 2; ni++) sacc[mi][ni] = fz;
        #pragma unroll
        for (int ks = 0; ks < 2; ks++) {
            #pragma unroll
            for (int ni = 0; ni < 2; ni++) {
                bf16x8 fb = *(const bf16x8*)&sHp[(ni * 16 + l15) * 72 + ks * 32 + quad * 8];
                #pragma unroll
                for (int mi = 0; mi < 2; mi++)
                    sacc[mi][ni] = MFMA_BF16(fa[mi][ks], fb, sacc[mi][ni]);
            }
        }
        // P = exp(S), write to LDS in A-layout
        #pragma unroll
        for (int mi = 0; mi < 2; mi++)
            #pragma unroll
            for (int ni = 0; ni < 2; ni++) {
                int lcol = ni * 16 + l15;
                bool lv = (l0 + lcol) < L_;
                #pragma unroll
                for (int r = 0; r < 4; r++) {
                    float p = lv ? __expf(sacc[mi][ni][r]) : 0.f;
                    sP[(w * 32 + mi * 16 + quad * 4 + r) * 40 + lcol] = f2bf(p);
                }
            }
        __syncthreads();

        // O += P [y×32l] · hp [32l×64f]
        bf16x8 fv[4];
        #pragma unroll
        for (int ni = 0; ni < 4; ni++)
            fv[ni] = *(const bf16x8*)&sHt[(ni * 16 + l15) * 40 + quad * 8];
        #pragma unroll
        for (int mi = 0; mi < 2; mi++) {
            bf16x8 fp_ = *(const bf16x8*)&sP[(w * 32 + mi * 16 + l15) * 40 + quad * 8];
            #pragma unroll
            for (int ni = 0; ni < 4; ni++)
                pacc[mi][ni] = MFMA_BF16(fp_, fv[ni], pacc[mi][ni]);
        }
    }

    // denominator column: f=50 -> ni=3, lane&15==2
    if (l15 == 2) {
        #pragma unroll
        for (int mi = 0; mi < 2; mi++)
            #pragma unroll
            for (int r = 0; r < 4; r++)
                sDen[w * 32 + mi * 16 + quad * 4 + r] = pacc[mi][3][r];
    }
    __syncthreads();

    #pragma unroll
    for (int mi = 0; mi < 2; mi++)
        #pragma unroll
        for (int ni = 0; ni < 4; ni++) {
            int f = ni * 16 + l15;
            if (f < F_) {
                #pragma unroll
                for (int r = 0; r < 4; r++) {
                    int yl = w * 32 + mi * 16 + quad * 4 + r;
                    int y = y0 + yl;
                    if (y < Y_)
                        m4t[((size_t)b * Y_ + y) * F_ + f] = pacc[mi][ni][r] / sDen[yl];
                }
            }
        }
}

// ---------------------------------------------------------------- support + y4t
// Bt tile image (per kt): u16[416*32], PRE-SWIZZLED so that k4's linear
// global_load_lds image gives conflict-free ds_read_b128:
//   image[n*32 + ((z>>3) ^ ((n>>1)&3))*8 + (z&7)] = bf16(support[n][z])
__global__ __launch_bounds__(256) void k3_support(
    const float* __restrict__ m4t, const float* __restrict__ gcn_w,
    const float* __restrict__ f4t_w, const float* __restrict__ f4t_b,
    u16* __restrict__ Bt, float* __restrict__ y4t_out)
{
    __shared__ float sW[50 * 52];   // gcn_w^T : [g][f], rows padded 52
    const int tid = threadIdx.x;
    for (int i = tid; i < 50 * 52; i += 256) {
        int g = i / 52, f = i - g * 52;
        sW[i] = (f < F_) ? gcn_w[f * F_ + g] : 0.f;
    }
    __syncthreads();

    const int b = blockIdx.y;
    const int y = blockIdx.x * 256 + tid;
    if (y >= Y_) return;

    float2 m[25];
    const float* mrow = m4t + ((size_t)b * Y_ + y) * F_;
    #pragma unroll
    for (int i = 0; i < 25; i++) m[i] = *(const float2*)(mrow + 2 * i);

    const int kt = y >> 5, zo = y & 31;
    const int zhi = zo >> 3, zlo = zo & 7;
    u16* btile = Bt + (size_t)kt * (NT_ * 32);
    for (int g = 0; g < F_; g++) {
        float s = 0.f;
        const float* wr = sW + g * 52;
        #pragma unroll
        for (int i = 0; i < 25; i++) {
            float2 wv = *(const float2*)(wr + 2 * i);
            s += m[i].x * wv.x + m[i].y * wv.y;
        }
        int n = b * F_ + g;
        btile[n * 32 + ((zhi ^ ((n >> 1) & 3)) << 3) + zlo] = f2bf(s);
    }

    const float* tw = f4t_w + (size_t)y * F_;
    float acc = f4t_b[y];
    #pragma unroll
    for (int i = 0; i < 25; i++) {
        float2 wv = *(const float2*)(tw + 2 * i);
        acc += m[i].x * wv.x + m[i].y * wv.y;
    }
    y4t_out[(size_t)b * Y_ + y] = acc;
}

// ---------------------------------------------------------------- adj GEMM
// Asymmetric-depth counted-vmcnt pipeline (unchanged from R5):
//   A (adj, HBM stream): 3 buffers -> staged 2 tiles ahead
//   B (Bt, L2/L3-resident): 2 buffers -> staged 1 tile ahead
// Per iter: issue B(t+1)[8] + A(t+2)[8]; single s_waitcnt vmcnt(24) proves
// B(t),A(t) landed (in-order retirement, m135); no vmcnt(0) in the loop.
// KP_=3 -> grid 420 <= 512-block co-residency: ONE dispatch wave.
__global__ __launch_bounds__(256, 2) void k4_gemm(
    const float* __restrict__ adj, const u16* __restrict__ Bt,
    float* __restrict__ outp)
{
    __shared__ float sA[3][64 * 32];    // fp32 A-tiles (swizzled image), 3x8 KB
    __shared__ u16   sB[2][NT_ * 32];   // bf16 B-tiles (pre-swizzled image), 2x26 KB

    const int tid  = threadIdx.x;
    const int bid  = blockIdx.x;
    const int kp   = bid % KP_;                     // 0..2
    const int mIdx = bid / KP_;                     // 0..139
    const int m0   = mIdx * 64;
    const int w    = tid >> 6;
    const int wq   = __builtin_amdgcn_readfirstlane(w);
    const int lane = tid & 63;
    const int l15  = lane & 15;
    const int quad = lane >> 4;
    const int wm   = w & 1;        // M sub-block (0..1) -> rows wm*32..+32
    const int wn   = w >> 1;       // N half (0..1) -> cols wn*208..+208

    // A staging: round j, thread t fills physical word j*256+t = (row, cphys).
    // logical col = ((cphys>>2) ^ (row&7))*4 + (cphys&3); row&7 == tid>>5 for all rounds.
    const int rA   = tid >> 5;                                       // 0..7
    const int colA = ((((tid & 31) >> 2) ^ rA) << 2) | (tid & 3);    // 0..31, round-invariant
    const unsigned rbaseA = (unsigned)(m0 + rA) * (unsigned)Y_ + (unsigned)colA;

    // lane-const swizzled read offsets
    const int r7    = l15 & 7;
    const int offA0 = (((2 * quad)     ^ r7) << 2);   // float offset of 1st 16B slot
    const int offA1 = (((2 * quad + 1) ^ r7) << 2);   // float offset of 2nd 16B slot
    const int offB  = ((quad ^ ((l15 >> 1) & 3)) << 3); // u16 offset of B slot

    const f32x4 fz = {0.f, 0.f, 0.f, 0.f};
    f32x4 acc[2][13];
    #pragma unroll
    for (int mi = 0; mi < 2; mi++)
        #pragma unroll
        for (int ni = 0; ni < 13; ni++) acc[mi][ni] = fz;

    // B stage = 8 loads/thread (6x glds16 + 2x glds4); A stage = 8 loads/thread (glds4)
    auto stageB = [&](int buf, int kt) {
        const char* bt = (const char*)Bt + (size_t)kt * (NT_ * 32 * 2);
        char* sb = (char*)sB[buf];
        #pragma unroll
        for (int j = 0; j < 6; j++)
            glds16(bt + j * 4096 + tid * 16, sb + j * 4096 + wq * 1024);
        #pragma unroll
        for (int j = 0; j < 2; j++)
            glds4(bt + 24576 + j * 1024 + tid * 4, sb + 24576 + j * 1024 + wq * 256);
    };
    auto stageA = [&](int buf, int kt) {
        char* sa = (char*)sA[buf];
        const unsigned idx0 = rbaseA + (unsigned)kt * 32u;
        #pragma unroll
        for (int j = 0; j < 8; j++) {
            unsigned idx = idx0 + (unsigned)(j * 8 * Y_);
            idx = (idx > (unsigned)AMAX_) ? (unsigned)AMAX_ : idx;   // OOB clamp (harmless rows/cols)
            glds4(adj + idx, sa + j * 1024 + wq * 256);
        }
    };

    // K-split: kp0 = [0,94) (94 tiles), kp1 = [94,187), kp2 = [187,280) (93 each)
    const int kt0   = (kp == 0) ? 0 : 1 + 93 * kp;
    const int niter = 93 + (kp == 0);
    const int ktmax = kt0 + niter - 1;
    // prologue issue order (vmcnt accounting depends on it): B0[8], A0[8], A1[8]
    stageB(0, kt0);
    stageA(0, kt0);
    stageA(1, kt0 + 1);

    int a0 = 0;   // A buffer index = t % 3
    for (int it = 0; it < niter; it++) {
        int ktb = kt0 + it + 1; if (ktb > ktmax) ktb = ktmax;
        int kta = kt0 + it + 2; if (kta > ktmax) kta = ktmax;
        stageB((it + 1) & 1, ktb);
        int a2 = a0 + 2; if (a2 >= 3) a2 -= 3;
        stageA(a2, kta);
        asm volatile("s_waitcnt vmcnt(24)" ::: "memory");   // B(t), A(t) landed
        __builtin_amdgcn_s_barrier();            // raw: no compiler drain
        __builtin_amdgcn_sched_barrier(0);

        const float* sAc = sA[a0];
        const u16*   sBc = sB[it & 1];
        bf16x8 fa[2];
        #pragma unroll
        for (int mi = 0; mi < 2; mi++) {
            const int rb = (wm * 32 + mi * 16 + l15) * 32;
            f32x4 x0 = *(const f32x4*)&sAc[rb + offA0];
            f32x4 x1 = *(const f32x4*)&sAc[rb + offA1];
            bf16x8 v;
            v[0] = (short)f2bf(x0[0]); v[1] = (short)f2bf(x0[1]);
            v[2] = (short)f2bf(x0[2]); v[3] = (short)f2bf(x0[3]);
            v[4] = (short)f2bf(x1[0]); v[5] = (short)f2bf(x1[1]);
            v[6] = (short)f2bf(x1[2]); v[7] = (short)f2bf(x1[3]);
            fa[mi] = v;
        }
        #pragma unroll
        for (int ni = 0; ni < 13; ni++) {
            bf16x8 fb = *(const bf16x8*)&sBc[(wn * 208 + ni * 16 + l15) * 32 + offB];
            acc[0][ni] = MFMA_BF16(fa[0], fb, acc[0][ni]);
            acc[1][ni] = MFMA_BF16(fa[1], fb, acc[1][ni]);
        }

        __builtin_amdgcn_sched_barrier(0);
        asm volatile("s_waitcnt lgkmcnt(0)" ::: "memory");   // reads of this tile done
        __builtin_amdgcn_s_barrier();            // raw: buffers free for overwrite
        __builtin_amdgcn_sched_barrier(0);       // pin next-iter glds below the barrier
        a0++; if (a0 >= 3) a0 = 0;
    }
    asm volatile("s_waitcnt vmcnt(0)" ::: "memory");   // drain dummy in-flight loads
    __builtin_amdgcn_sched_barrier(0);

    float* dst = outp + (size_t)kp * Y_ * 400;
    #pragma unroll
    for (int mi = 0; mi < 2; mi++)
        #pragma unroll
        for (int ni = 0; ni < 13; ni++) {
            int n = wn * 208 + ni * 16 + l15;
            if (n < 400) {
                #pragma unroll
                for (int r4 = 0; r4 < 4; r4++) {
                    int y = m0 + wm * 32 + mi * 16 + quad * 4 + r4;
                    if (y < Y_) dst[(size_t)y * 400 + n] = acc[mi][ni][r4];
                }
            }
        }
}

// ---------------------------------------------------------------- final y4
__global__ __launch_bounds__(256) void k5_final(
    const float* __restrict__ outp, const float* __restrict__ m4t,
    const float* __restrict__ gcn_b, const float* __restrict__ f4_w,
    const float* __restrict__ f4_b, float* __restrict__ y4_out)
{
    const int b = blockIdx.y;
    const int y = blockIdx.x * 256 + threadIdx.x;
    if (y >= Y_) return;

    const size_t PS = (size_t)Y_ * 400;
    const float* p0 = outp + (size_t)y * 400 + b * F_;
    const float* fw = f4_w + (size_t)y * 100;
    const float* mrow = m4t + ((size_t)b * Y_ + y) * F_;

    float acc = f4_b[y];
    #pragma unroll
    for (int i = 0; i < 25; i++) {
        float2 mv = *(const float2*)(mrow + 2 * i);
        float2 wv = *(const float2*)(fw + 2 * i);
        acc += mv.x * wv.x + mv.y * wv.y;
    }
    #pragma unroll
    for (int i = 0; i < 25; i++) {
        float sx = 0.f, sy = 0.f;
        #pragma unroll
        for (int kp = 0; kp < KP_; kp++) {
            float2 v = *(const float2*)(p0 + kp * PS + 2 * i);
            sx += v.x; sy += v.y;
        }
        float2 gb = *(const float2*)(gcn_b + 2 * i);
        sx += gb.x; sy += gb.y;
        sx = sx > 0.f ? sx : 0.2f * sx;   // leaky_relu
        sy = sy > 0.f ? sy : 0.2f * sy;
        float2 wv = *(const float2*)(fw + 50 + 2 * i);
        acc += sx * wv.x + sy * wv.y;
    }
    y4_out[(size_t)b * Y_ + y] = acc;
}

// ---------------------------------------------------------------- launch
extern "C" void kernel_launch(void* const* d_in, const int* in_sizes, int n_in,
                              void* d_out, int out_size, void* d_ws, size_t ws_size,
                              hipStream_t stream) {
    const int*   x       = (const int*)d_in[0];
    const float* embed_w = (const float*)d_in[2];
    const float* conv_w  = (const float*)d_in[3];
    const float* conv_b  = (const float*)d_in[4];
    const float* U4_w    = (const float*)d_in[5];
    const float* gcn_w   = (const float*)d_in[6];
    const float* gcn_b   = (const float*)d_in[7];
    const float* adj     = (const float*)d_in[8];
    const float* f4t_w   = (const float*)d_in[9];
    const float* f4t_b   = (const float*)d_in[10];
    const float* f4_w    = (const float*)d_in[11];
    const float* f4_b    = (const float*)d_in[12];
    float* out = (float*)d_out;

    char* ws = (char*)d_ws;
    const size_t SZ_WT  = 180224;                            // 9*50*100*4 rounded
    const size_t SZ_HP  = (size_t)B_ * LP * 64 * 2;          // 2,588,672
    const size_t SZ_BT  = (size_t)KT_ * NT_ * 32 * 2;        // 7,454,720
    const size_t SZ_M4T = (size_t)B_ * Y_ * F_ * 4;          // 14,275,200
    int*   flag = (int*)ws;
    float* wT   = (float*)(ws + 16);
    u16*   hp   = (u16*)(ws + 16 + SZ_WT);
    u16*   hpT  = (u16*)(ws + 16 + SZ_WT + SZ_HP);
    u16*   Bt   = (u16*)(ws + 16 + SZ_WT + 2 * SZ_HP);
    float* m4t  = (float*)(ws + 16 + SZ_WT + 2 * SZ_HP + SZ_BT);
    float* outp = (float*)(ws + 16 + SZ_WT + 2 * SZ_HP + SZ_BT + SZ_M4T);  // KP_*Y*400*4 = 43 MB

    k0_prep<<<9, 256, 0, stream>>>(x, conv_w, flag, wT);
    k1_conv<<<dim3(40, 8), 256, 0, stream>>>(x, flag, embed_w, wT, conv_b, hp, hpT);
    hipMemsetAsync(Bt, 0, SZ_BT, stream);
    k2_attn<<<dim3(70, 8), 256, 0, stream>>>(U4_w, hp, hpT, m4t);
    k3_support<<<dim3(35, 8), 256, 0, stream>>>(m4t, gcn_w, f4t_w, f4t_b, Bt, out);
    k4_gemm<<<dim3(140 * KP_), 256, 0, stream>>>(adj, Bt, outp);
    k5_final<<<dim3(35, 8), 256, 0, stream>>>(outp, m4t, gcn_b, f4_w, f4_b,
                                              out + (size_t)B_ * Y_);
}

// Round 7
// 829.931 us; speedup vs baseline: 1.1692x; 1.0441x over previous
//
#include <hip/hip_runtime.h>

typedef unsigned short u16;
typedef short bf16x8 __attribute__((ext_vector_type(8)));   // MFMA A/B frag (8 bf16)
typedef float f32x4  __attribute__((ext_vector_type(4)));   // MFMA C/D frag
typedef u16   u16x8  __attribute__((ext_vector_type(8)));   // 16B vector ld/st

#define MFMA_BF16(a, b, c) __builtin_amdgcn_mfma_f32_16x16x32_bf16((a), (b), (c), 0, 0, 0)

#define B_  8
#define L_  2500
#define LP  2528          // L padded to 79*32
#define E_  100
#define F_  50
#define Y_  8922
#define YP  8960          // Y padded to 280*32
#define KT_ 280           // K tiles of 32 over YP
#define NT_ 416           // N = B*F = 400 padded to 26*16
#define KP_ 3             // K-split: parts of 94/93/93 tiles
#define AMAX_ (Y_ * Y_ - 1)

__device__ __forceinline__ u16 f2bf(float f) {
    unsigned int x = __float_as_uint(f);
    unsigned int r = x + 0x7fffu + ((x >> 16) & 1u);   // RNE
    return (u16)(r >> 16);
}

// direct global->LDS copies (wave-uniform LDS base + lane*size, per-lane global src)
__device__ __forceinline__ void glds16(const void* g, const void* l) {
    __builtin_amdgcn_global_load_lds(
        (const __attribute__((address_space(1))) unsigned int*)(unsigned long long)g,
        (__attribute__((address_space(3))) unsigned int*)(unsigned int)(unsigned long long)l,
        16, 0, 0);
}
__device__ __forceinline__ void glds4(const void* g, const void* l) {
    __builtin_amdgcn_global_load_lds(
        (const __attribute__((address_space(1))) unsigned int*)(unsigned long long)g,
        (__attribute__((address_space(3))) unsigned int*)(unsigned int)(unsigned long long)l,
        4, 0, 0);
}

// ---------------------------------------------------------------- prep
__global__ __launch_bounds__(256) void k0_prep(
    const int* __restrict__ x, const float* __restrict__ conv_w,
    int* __restrict__ flag, float* __restrict__ wT)
{
    const int k = blockIdx.x;           // 0..8
    const int tid = threadIdx.x;
    if (k == 0 && tid == 0) {
        int nz = 0;
        #pragma unroll
        for (int i = 0; i < 32; i++) nz |= x[2 * i + 1];
        *flag = (nz == 0) ? 1 : 0;      // all-high-words-zero => int64 buffer
    }
    for (int j = tid; j < 5000; j += 256)           // j = f*100 + e
        wT[k * 5000 + j] = conv_w[j * 9 + k];
}

// ---------------------------------------------------------------- conv (fp32)
// R5 rework (kept): uniform wT reads from L2, 13-way batched loads,
// conflict-free sEmb stride 108.
__global__ __launch_bounds__(256) void k1_conv(
    const int* __restrict__ x, const int* __restrict__ flag,
    const float* __restrict__ embed_w, const float* __restrict__ wT,
    const float* __restrict__ conv_b,
    u16* __restrict__ hp, u16* __restrict__ hpT)
{
    __shared__ float sEmb[72 * 108];   // 72 rows (64 + 8 halo), stride 108
    __shared__ int   sId[72];
    const int tid = threadIdx.x;
    const int b  = blockIdx.y;
    const int l0 = blockIdx.x * 64;
    const int is64 = *flag;

    if (tid < 72) {
        int l = l0 - 4 + tid;
        int id = -1;
        if (l >= 0 && l < L_) id = is64 ? x[(b * L_ + l) * 2] : x[b * L_ + l];
        sId[tid] = id;
    }
    __syncthreads();
    for (int i = tid; i < 72 * 25; i += 256) {       // float4 granules
        int r = i / 25, e4 = i - r * 25;
        int id = sId[r];
        float4 v = make_float4(0.f, 0.f, 0.f, 0.f);
        if (id >= 0) v = *(const float4*)&embed_w[(size_t)id * 100 + e4 * 4];
        *(float4*)&sEmb[r * 108 + e4 * 4] = v;
    }
    __syncthreads();

    const int li = tid & 63;
    const int fg = __builtin_amdgcn_readfirstlane(tid >> 6);   // wave-uniform f-group 0..3

    int fidx[13];     // clamped f per slot (uniform); duplicate f=49 compute for
    #pragma unroll    // fg>=2 slot 12 is discarded by the f<F_ store guard
    for (int i = 0; i < 13; i++) { int f = fg + 4 * i; fidx[i] = (f < F_) ? f : 49; }

    float acc[13];
    #pragma unroll
    for (int i = 0; i < 13; i++) { int f = fg + 4 * i; acc[i] = (f < F_) ? conv_b[f] : 0.f; }

    for (int k = 0; k < 9; k++) {
        const float* wk = wT + k * 5000;
        for (int e4 = 0; e4 < 25; e4++) {
            float4 h = *(const float4*)&sEmb[(li + k) * 108 + e4 * 4];
            #pragma unroll
            for (int i = 0; i < 13; i++) {     // 13 independent uniform loads batch
                float4 w = *(const float4*)&wk[fidx[i] * 100 + e4 * 4];
                acc[i] += h.x * w.x + h.y * w.y + h.z * w.z + h.w * w.w;
            }
        }
    }

    int l = l0 + li;
    if (l < LP) {
        bool valid = (l < L_);
        #pragma unroll
        for (int i = 0; i < 13; i++) {
            int f = fg + 4 * i;
            if (f < F_) {
                u16 hv = 0;
                if (valid) {
                    float e2 = __expf(2.f * acc[i]);
                    hv = f2bf((e2 - 1.f) / (e2 + 1.f));   // tanh
                }
                hp [((size_t)b * LP + l) * 64 + f] = hv;
                hpT[((size_t)b * 64 + f) * LP + l] = hv;
            }
        }
        #pragma unroll
        for (int j = 0; j < 4; j++) {
            int f = 50 + fg + 4 * j;
            if (f < 64) {
                hp [((size_t)b * LP + l) * 64 + f] = 0;
                hpT[((size_t)b * 64 + f) * LP + l] = (f == 50 && valid) ? f2bf(1.f) : (u16)0;
            }
        }
    }
}

// ---------------------------------------------------------------- flash attention (reg-prefetch pipelined)
__global__ __launch_bounds__(256) void k2_attn(
    const float* __restrict__ U4_w,
    const u16* __restrict__ hp, const u16* __restrict__ hpT,
    float* __restrict__ m4t)
{
    __shared__ u16  sU4[128 * 72];   // [y][f] f-contig, rows padded 72
    __shared__ u16  sHp[32 * 72];    // [l][f] f-contig (S-GEMM B)
    __shared__ u16  sHt[64 * 40];    // [f][l] l-contig (PV B), rows padded 40
    __shared__ u16  sP [128 * 40];   // [y][l] l-contig (PV A)
    __shared__ float sDen[128];

    const int tid  = threadIdx.x;
    const int b    = blockIdx.y;
    const int y0   = blockIdx.x * 128;
    const int w    = tid >> 6;
    const int lane = tid & 63;
    const int l15  = lane & 15;
    const int quad = lane >> 4;

    for (int i = tid; i < 128 * 72; i += 256) {
        int r = i / 72, c = i - r * 72;
        float v = 0.f;
        int y = y0 + r;
        if (c < F_ && y < Y_) v = U4_w[y * F_ + c];
        sU4[i] = f2bf(v);
    }
    __syncthreads();

    bf16x8 fa[2][2];   // hoisted U4 A-frags
    #pragma unroll
    for (int mi = 0; mi < 2; mi++)
        #pragma unroll
        for (int ks = 0; ks < 2; ks++)
            fa[mi][ks] = *(const bf16x8*)&sU4[(w * 32 + mi * 16 + l15) * 72 + ks * 32 + quad * 8];

    const f32x4 fz = {0.f, 0.f, 0.f, 0.f};
    f32x4 pacc[2][4];
    #pragma unroll
    for (int mi = 0; mi < 2; mi++)
        #pragma unroll
        for (int ni = 0; ni < 4; ni++) pacc[mi][ni] = fz;

    // staging coords + prefetch regs
    const int rr = tid >> 3, seg = tid & 7;      // hp tile [32][64]
    const int fr = tid >> 2, s2 = tid & 3;       // hpT tile [64][32]
    u16x8 pv, pv2;
    {
        pv  = *(const u16x8*)&hp [((size_t)b * LP + rr) * 64 + seg * 8];
        pv2 = *(const u16x8*)&hpT[((size_t)b * 64 + fr) * LP + s2 * 8];
    }

    for (int lt = 0; lt < 79; lt++) {
        const int l0 = lt * 32;
        __syncthreads();
        *(u16x8*)&sHp[rr * 72 + seg * 8] = pv;
        *(u16x8*)&sHt[fr * 40 + s2 * 8] = pv2;
        if (lt + 1 < 79) {   // prefetch next tile; latency hidden under S+PV compute
            const int ln = l0 + 32;
            pv  = *(const u16x8*)&hp [((size_t)b * LP + ln + rr) * 64 + seg * 8];
            pv2 = *(const u16x8*)&hpT[((size_t)b * 64 + fr) * LP + ln + s2 * 8];
        }
        __syncthreads();

        // S = U4p [y×64f] · hp^T [64f×l]
        f32x4 sacc[2][2];
        #pragma unroll
        for (int mi = 0; mi < 2; mi++)
            #pragma unroll
            for (int ni = 0; ni < 2; ni++) sacc[mi][ni] = fz;
        #pragma unroll
        for (int ks = 0; ks < 2; ks++) {
            #pragma unroll
            for (int ni = 0; ni < 2; ni++) {
                bf16x8 fb = *(const bf16x8*)&sHp[(ni * 16 + l15) * 72 + ks * 32 + quad * 8];
                #pragma unroll
                for (int mi = 0; mi < 2; mi++)
                    sacc[mi][ni] = MFMA_BF16(fa[mi][ks], fb, sacc[mi][ni]);
            }
        }
        // P = exp(S), write to LDS in A-layout (rows w*32..w*32+31: WAVE-PRIVATE)
        #pragma unroll
        for (int mi = 0; mi < 2; mi++)
            #pragma unroll
            for (int ni = 0; ni < 2; ni++) {
                int lcol = ni * 16 + l15;
                bool lv = (l0 + lcol) < L_;
                #pragma unroll
                for (int r = 0; r < 4; r++) {
                    float p = lv ? __expf(sacc[mi][ni][r]) : 0.f;
                    sP[(w * 32 + mi * 16 + quad * 4 + r) * 40 + lcol] = f2bf(p);
                }
            }
        // sP is wave-private (each wave writes+reads only its own 32-row band);
        // sHt was staged before the 2nd barrier -> wave-local lgkmcnt suffices,
        // no block barrier needed here (saves 79 barriers).
        asm volatile("s_waitcnt lgkmcnt(0)" ::: "memory");
        __builtin_amdgcn_sched_barrier(0);

        // O += P [y×32l] · hp [32l×64f]
        bf16x8 fv[4];
        #pragma unroll
        for (int ni = 0; ni < 4; ni++)
            fv[ni] = *(const bf16x8*)&sHt[(ni * 16 + l15) * 40 + quad * 8];
        #pragma unroll
        for (int mi = 0; mi < 2; mi++) {
            bf16x8 fp_ = *(const bf16x8*)&sP[(w * 32 + mi * 16 + l15) * 40 + quad * 8];
            #pragma unroll
            for (int ni = 0; ni < 4; ni++)
                pacc[mi][ni] = MFMA_BF16(fp_, fv[ni], pacc[mi][ni]);
        }
    }

    // denominator column: f=50 -> ni=3, lane&15==2
    if (l15 == 2) {
        #pragma unroll
        for (int mi = 0; mi < 2; mi++)
            #pragma unroll
            for (int r = 0; r < 4; r++)
                sDen[w * 32 + mi * 16 + quad * 4 + r] = pacc[mi][3][r];
    }
    __syncthreads();

    #pragma unroll
    for (int mi = 0; mi < 2; mi++)
        #pragma unroll
        for (int ni = 0; ni < 4; ni++) {
            int f = ni * 16 + l15;
            if (f < F_) {
                #pragma unroll
                for (int r = 0; r < 4; r++) {
                    int yl = w * 32 + mi * 16 + quad * 4 + r;
                    int y = y0 + yl;
                    if (y < Y_)
                        m4t[((size_t)b * Y_ + y) * F_ + f] = pacc[mi][ni][r] / sDen[yl];
                }
            }
        }
}

// ---------------------------------------------------------------- support + y4t
// Bt tile image (per kt): u16[416*32], PRE-SWIZZLED so that k4's linear
// global_load_lds image gives conflict-free ds_read_b128:
//   image[n*32 + ((z>>3) ^ ((n>>1)&3))*8 + (z&7)] = bf16(support[n][z])
__global__ __launch_bounds__(256) void k3_support(
    const float* __restrict__ m4t, const float* __restrict__ gcn_w,
    const float* __restrict__ f4t_w, const float* __restrict__ f4t_b,
    u16* __restrict__ Bt, float* __restrict__ y4t_out)
{
    __shared__ float sW[50 * 52];   // gcn_w^T : [g][f], rows padded 52
    const int tid = threadIdx.x;
    for (int i = tid; i < 50 * 52; i += 256) {
        int g = i / 52, f = i - g * 52;
        sW[i] = (f < F_) ? gcn_w[f * F_ + g] : 0.f;
    }
    __syncthreads();

    const int b = blockIdx.y;
    const int y = blockIdx.x * 256 + tid;
    if (y >= Y_) return;

    float2 m[25];
    const float* mrow = m4t + ((size_t)b * Y_ + y) * F_;
    #pragma unroll
    for (int i = 0; i < 25; i++) m[i] = *(const float2*)(mrow + 2 * i);

    const int kt = y >> 5, zo = y & 31;
    const int zhi = zo >> 3, zlo = zo & 7;
    u16* btile = Bt + (size_t)kt * (NT_ * 32);
    for (int g = 0; g < F_; g++) {
        float s = 0.f;
        const float* wr = sW + g * 52;
        #pragma unroll
        for (int i = 0; i < 25; i++) {
            float2 wv = *(const float2*)(wr + 2 * i);
            s += m[i].x * wv.x + m[i].y * wv.y;
        }
        int n = b * F_ + g;
        btile[n * 32 + ((zhi ^ ((n >> 1) & 3)) << 3) + zlo] = f2bf(s);
    }

    const float* tw = f4t_w + (size_t)y * F_;
    float acc = f4t_b[y];
    #pragma unroll
    for (int i = 0; i < 25; i++) {
        float2 wv = *(const float2*)(tw + 2 * i);
        acc += m[i].x * wv.x + m[i].y * wv.y;
    }
    y4t_out[(size_t)b * Y_ + y] = acc;
}

// ---------------------------------------------------------------- adj GEMM
// R6 rework: BM 64 -> 128 (512-thread blocks, 8 waves: 4 in M x 2 in N).
// Rationale: B-refetch traffic = (Y/BM) * 7.45MB was 1.04 GB through L3 at
// BM=64 (~7.8 TB/s over 133us = the binding constraint). BM=128 halves it
// to 520 MB and halves block count (grid 210, 1 block/CU @ 102 KB LDS,
// 8 waves = 2/SIMD -> same waves/CU as before).
// Counted-vmcnt pipeline re-derived: per iter issue B(t+1)[4] + A(t+2)[8]
// = 12 loads/thread; steady outstanding 32 -> s_waitcnt vmcnt(20) retires
// exactly A(t)+B(t). A 3-buf (depth 2), B 2-buf (depth 1). No vmcnt(0) in
// the loop. Swizzle images unchanged (rule 21 both-sides discipline).
__global__ __launch_bounds__(512, 2) void k4_gemm(
    const float* __restrict__ adj, const u16* __restrict__ Bt,
    float* __restrict__ outp)
{
    __shared__ float sA[3][128 * 32];   // fp32 A-tiles (swizzled image), 3x16 KB
    __shared__ u16   sB[2][NT_ * 32];   // bf16 B-tiles (pre-swizzled image), 2x26 KB
                                        // total 102400 B -> 1 block/CU

    const int tid  = threadIdx.x;
    const int bid  = blockIdx.x;
    const int kp   = bid % KP_;                     // 0..2
    const int mIdx = bid / KP_;                     // 0..69
    const int m0   = mIdx * 128;
    const int w    = tid >> 6;                      // 0..7
    const int wq   = __builtin_amdgcn_readfirstlane(w);
    const int lane = tid & 63;
    const int l15  = lane & 15;
    const int quad = lane >> 4;
    const int wm   = w & 3;        // M sub-block (0..3) -> rows wm*32..+32
    const int wn   = w >> 2;       // N half (0..1) -> cols wn*208..+208

    // A staging: round j (0..7), thread t fills physical word j*512+t = (row, cphys),
    // row = j*16 + (t>>5), cphys = t&31. Logical col = ((cphys>>2)^(row&7))*4+(cphys&3);
    // row&7 = (t>>5)&7 is round-invariant (j*16 % 8 == 0).
    const int rA   = tid >> 5;                                        // 0..15
    const int colA = ((((tid & 31) >> 2) ^ (rA & 7)) << 2) | (tid & 3);
    const unsigned rbaseA = (unsigned)(m0 + rA) * (unsigned)Y_ + (unsigned)colA;

    // lane-const swizzled read offsets
    const int r7    = l15 & 7;
    const int offA0 = (((2 * quad)     ^ r7) << 2);   // float offset of 1st 16B slot
    const int offA1 = (((2 * quad + 1) ^ r7) << 2);   // float offset of 2nd 16B slot
    const int offB  = ((quad ^ ((l15 >> 1) & 3)) << 3); // u16 offset of B slot

    const f32x4 fz = {0.f, 0.f, 0.f, 0.f};
    f32x4 acc[2][13];
    #pragma unroll
    for (int mi = 0; mi < 2; mi++)
        #pragma unroll
        for (int ni = 0; ni < 13; ni++) acc[mi][ni] = fz;

    // B stage = 4 loads/thread (3x glds16 + 1x glds4 = 26624 B exactly);
    // A stage = 8 loads/thread (glds4, 16384 B)
    auto stageB = [&](int buf, int kt) {
        const char* bt = (const char*)Bt + (size_t)kt * (NT_ * 32 * 2);
        char* sb = (char*)sB[buf];
        #pragma unroll
        for (int j = 0; j < 3; j++)
            glds16(bt + j * 8192 + tid * 16, sb + j * 8192 + wq * 1024);
        glds4(bt + 24576 + tid * 4, sb + 24576 + wq * 256);
    };
    auto stageA = [&](int buf, int kt) {
        char* sa = (char*)sA[buf];
        const unsigned idx0 = rbaseA + (unsigned)kt * 32u;
        #pragma unroll
        for (int j = 0; j < 8; j++) {
            unsigned idx = idx0 + (unsigned)(j * 16 * Y_);
            idx = (idx > (unsigned)AMAX_) ? (unsigned)AMAX_ : idx;   // OOB clamp (harmless rows/cols)
            glds4(adj + idx, sa + j * 2048 + wq * 256);
        }
    };

    // K-split: kp0 = [0,94) (94 tiles), kp1 = [94,187), kp2 = [187,280) (93 each)
    const int kt0   = (kp == 0) ? 0 : 1 + 93 * kp;
    const int niter = 93 + (kp == 0);
    const int ktmax = kt0 + niter - 1;
    // prologue issue order (vmcnt accounting depends on it): B0[4], A0[8], A1[8]
    stageB(0, kt0);
    stageA(0, kt0);
    stageA(1, kt0 + 1);

    int a0 = 0;   // A buffer index = t % 3
    for (int it = 0; it < niter; it++) {
        int ktb = kt0 + it + 1; if (ktb > ktmax) ktb = ktmax;
        int kta = kt0 + it + 2; if (kta > ktmax) kta = ktmax;
        stageB((it + 1) & 1, ktb);
        int a2 = a0 + 2; if (a2 >= 3) a2 -= 3;
        stageA(a2, kta);
        asm volatile("s_waitcnt vmcnt(20)" ::: "memory");   // B(t), A(t) landed
        __builtin_amdgcn_s_barrier();            // raw: no compiler drain
        __builtin_amdgcn_sched_barrier(0);

        const float* sAc = sA[a0];
        const u16*   sBc = sB[it & 1];
        bf16x8 fa[2];
        #pragma unroll
        for (int mi = 0; mi < 2; mi++) {
            const int rb = (wm * 32 + mi * 16 + l15) * 32;
            f32x4 x0 = *(const f32x4*)&sAc[rb + offA0];
            f32x4 x1 = *(const f32x4*)&sAc[rb + offA1];
            bf16x8 v;
            v[0] = (short)f2bf(x0[0]); v[1] = (short)f2bf(x0[1]);
            v[2] = (short)f2bf(x0[2]); v[3] = (short)f2bf(x0[3]);
            v[4] = (short)f2bf(x1[0]); v[5] = (short)f2bf(x1[1]);
            v[6] = (short)f2bf(x1[2]); v[7] = (short)f2bf(x1[3]);
            fa[mi] = v;
        }
        #pragma unroll
        for (int ni = 0; ni < 13; ni++) {
            bf16x8 fb = *(const bf16x8*)&sBc[(wn * 208 + ni * 16 + l15) * 32 + offB];
            acc[0][ni] = MFMA_BF16(fa[0], fb, acc[0][ni]);
            acc[1][ni] = MFMA_BF16(fa[1], fb, acc[1][ni]);
        }

        __builtin_amdgcn_sched_barrier(0);
        asm volatile("s_waitcnt lgkmcnt(0)" ::: "memory");   // reads of this tile done
        __builtin_amdgcn_s_barrier();            // raw: buffers free for overwrite
        __builtin_amdgcn_sched_barrier(0);       // pin next-iter glds below the barrier
        a0++; if (a0 >= 3) a0 = 0;
    }
    asm volatile("s_waitcnt vmcnt(0)" ::: "memory");   // drain dummy in-flight loads
    __builtin_amdgcn_sched_barrier(0);

    float* dst = outp + (size_t)kp * Y_ * 400;
    #pragma unroll
    for (int mi = 0; mi < 2; mi++)
        #pragma unroll
        for (int ni = 0; ni < 13; ni++) {
            int n = wn * 208 + ni * 16 + l15;
            if (n < 400) {
                #pragma unroll
                for (int r4 = 0; r4 < 4; r4++) {
                    int y = m0 + wm * 32 + mi * 16 + quad * 4 + r4;
                    if (y < Y_) dst[(size_t)y * 400 + n] = acc[mi][ni][r4];
                }
            }
        }
}

// ---------------------------------------------------------------- final y4
__global__ __launch_bounds__(256) void k5_final(
    const float* __restrict__ outp, const float* __restrict__ m4t,
    const float* __restrict__ gcn_b, const float* __restrict__ f4_w,
    const float* __restrict__ f4_b, float* __restrict__ y4_out)
{
    const int b = blockIdx.y;
    const int y = blockIdx.x * 256 + threadIdx.x;
    if (y >= Y_) return;

    const size_t PS = (size_t)Y_ * 400;
    const float* p0 = outp + (size_t)y * 400 + b * F_;
    const float* fw = f4_w + (size_t)y * 100;
    const float* mrow = m4t + ((size_t)b * Y_ + y) * F_;

    float acc = f4_b[y];
    #pragma unroll
    for (int i = 0; i < 25; i++) {
        float2 mv = *(const float2*)(mrow + 2 * i);
        float2 wv = *(const float2*)(fw + 2 * i);
        acc += mv.x * wv.x + mv.y * wv.y;
    }
    #pragma unroll
    for (int i = 0; i < 25; i++) {
        float sx = 0.f, sy = 0.f;
        #pragma unroll
        for (int kp = 0; kp < KP_; kp++) {
            float2 v = *(const float2*)(p0 + kp * PS + 2 * i);
            sx += v.x; sy += v.y;
        }
        float2 gb = *(const float2*)(gcn_b + 2 * i);
        sx += gb.x; sy += gb.y;
        sx = sx > 0.f ? sx : 0.2f * sx;   // leaky_relu
        sy = sy > 0.f ? sy : 0.2f * sy;
        float2 wv = *(const float2*)(fw + 50 + 2 * i);
        acc += sx * wv.x + sy * wv.y;
    }
    y4_out[(size_t)b * Y_ + y] = acc;
}

// ---------------------------------------------------------------- launch
extern "C" void kernel_launch(void* const* d_in, const int* in_sizes, int n_in,
                              void* d_out, int out_size, void* d_ws, size_t ws_size,
                              hipStream_t stream) {
    const int*   x       = (const int*)d_in[0];
    const float* embed_w = (const float*)d_in[2];
    const float* conv_w  = (const float*)d_in[3];
    const float* conv_b  = (const float*)d_in[4];
    const float* U4_w    = (const float*)d_in[5];
    const float* gcn_w   = (const float*)d_in[6];
    const float* gcn_b   = (const float*)d_in[7];
    const float* adj     = (const float*)d_in[8];
    const float* f4t_w   = (const float*)d_in[9];
    const float* f4t_b   = (const float*)d_in[10];
    const float* f4_w    = (const float*)d_in[11];
    const float* f4_b    = (const float*)d_in[12];
    float* out = (float*)d_out;

    char* ws = (char*)d_ws;
    const size_t SZ_WT  = 180224;                            // 9*50*100*4 rounded
    const size_t SZ_HP  = (size_t)B_ * LP * 64 * 2;          // 2,588,672
    const size_t SZ_BT  = (size_t)KT_ * NT_ * 32 * 2;        // 7,454,720
    const size_t SZ_M4T = (size_t)B_ * Y_ * F_ * 4;          // 14,275,200
    int*   flag = (int*)ws;
    float* wT   = (float*)(ws + 16);
    u16*   hp   = (u16*)(ws + 16 + SZ_WT);
    u16*   hpT  = (u16*)(ws + 16 + SZ_WT + SZ_HP);
    u16*   Bt   = (u16*)(ws + 16 + SZ_WT + 2 * SZ_HP);
    float* m4t  = (float*)(ws + 16 + SZ_WT + 2 * SZ_HP + SZ_BT);
    float* outp = (float*)(ws + 16 + SZ_WT + 2 * SZ_HP + SZ_BT + SZ_M4T);  // KP_*Y*400*4 = 43 MB

    k0_prep<<<9, 256, 0, stream>>>(x, conv_w, flag, wT);
    k1_conv<<<dim3(40, 8), 256, 0, stream>>>(x, flag, embed_w, wT, conv_b, hp, hpT);
    hipMemsetAsync(Bt, 0, SZ_BT, stream);
    k2_attn<<<dim3(70, 8), 256, 0, stream>>>(U4_w, hp, hpT, m4t);
    k3_support<<<dim3(35, 8), 256, 0, stream>>>(m4t, gcn_w, f4t_w, f4t_b, Bt, out);
    k4_gemm<<<dim3(70 * KP_), 512, 0, stream>>>(adj, Bt, outp);
    k5_final<<<dim3(35, 8), 256, 0, stream>>>(outp, m4t, gcn_b, f4_w, f4_b,
                                              out + (size_t)B_ * Y_);
}

// Round 8
// 823.966 us; speedup vs baseline: 1.1777x; 1.0072x over previous
//
#include <hip/hip_runtime.h>

typedef unsigned short u16;
typedef short bf16x8 __attribute__((ext_vector_type(8)));   // MFMA A/B frag (8 bf16)
typedef float f32x4  __attribute__((ext_vector_type(4)));   // MFMA C/D frag
typedef u16   u16x8  __attribute__((ext_vector_type(8)));   // 16B vector ld/st

#define MFMA_BF16(a, b, c) __builtin_amdgcn_mfma_f32_16x16x32_bf16((a), (b), (c), 0, 0, 0)

#define B_  8
#define L_  2500
#define LP  2528          // L padded to 79*32
#define E_  100
#define F_  50
#define Y_  8922
#define YP  8960          // Y padded to 280*32
#define KT_ 280           // K tiles of 32 over YP
#define NT_ 416           // N = B*F = 400 padded to 26*16
#define KP_ 3             // K-split: parts of 94/93/93 tiles
#define AMAX_ (Y_ * Y_ - 1)

__device__ __forceinline__ u16 f2bf(float f) {
    unsigned int x = __float_as_uint(f);
    unsigned int r = x + 0x7fffu + ((x >> 16) & 1u);   // RNE
    return (u16)(r >> 16);
}

// direct global->LDS copies (wave-uniform LDS base + lane*size, per-lane global src)
__device__ __forceinline__ void glds16(const void* g, const void* l) {
    __builtin_amdgcn_global_load_lds(
        (const __attribute__((address_space(1))) unsigned int*)(unsigned long long)g,
        (__attribute__((address_space(3))) unsigned int*)(unsigned int)(unsigned long long)l,
        16, 0, 0);
}
__device__ __forceinline__ void glds4(const void* g, const void* l) {
    __builtin_amdgcn_global_load_lds(
        (const __attribute__((address_space(1))) unsigned int*)(unsigned long long)g,
        (__attribute__((address_space(3))) unsigned int*)(unsigned int)(unsigned long long)l,
        4, 0, 0);
}

// ---------------------------------------------------------------- prep
__global__ __launch_bounds__(256) void k0_prep(
    const int* __restrict__ x, const float* __restrict__ conv_w,
    int* __restrict__ flag, float* __restrict__ wT)
{
    const int k = blockIdx.x;           // 0..8
    const int tid = threadIdx.x;
    if (k == 0 && tid == 0) {
        int nz = 0;
        #pragma unroll
        for (int i = 0; i < 32; i++) nz |= x[2 * i + 1];
        *flag = (nz == 0) ? 1 : 0;      // all-high-words-zero => int64 buffer
    }
    for (int j = tid; j < 5000; j += 256)           // j = f*100 + e
        wT[k * 5000 + j] = conv_w[j * 9 + k];
}

// ---------------------------------------------------------------- conv (fp32)
// R5 rework (kept): uniform wT reads from L2, 13-way batched loads,
// conflict-free sEmb stride 108.
__global__ __launch_bounds__(256) void k1_conv(
    const int* __restrict__ x, const int* __restrict__ flag,
    const float* __restrict__ embed_w, const float* __restrict__ wT,
    const float* __restrict__ conv_b,
    u16* __restrict__ hp, u16* __restrict__ hpT)
{
    __shared__ float sEmb[72 * 108];   // 72 rows (64 + 8 halo), stride 108
    __shared__ int   sId[72];
    const int tid = threadIdx.x;
    const int b  = blockIdx.y;
    const int l0 = blockIdx.x * 64;
    const int is64 = *flag;

    if (tid < 72) {
        int l = l0 - 4 + tid;
        int id = -1;
        if (l >= 0 && l < L_) id = is64 ? x[(b * L_ + l) * 2] : x[b * L_ + l];
        sId[tid] = id;
    }
    __syncthreads();
    for (int i = tid; i < 72 * 25; i += 256) {       // float4 granules
        int r = i / 25, e4 = i - r * 25;
        int id = sId[r];
        float4 v = make_float4(0.f, 0.f, 0.f, 0.f);
        if (id >= 0) v = *(const float4*)&embed_w[(size_t)id * 100 + e4 * 4];
        *(float4*)&sEmb[r * 108 + e4 * 4] = v;
    }
    __syncthreads();

    const int li = tid & 63;
    const int fg = __builtin_amdgcn_readfirstlane(tid >> 6);   // wave-uniform f-group 0..3

    int fidx[13];     // clamped f per slot (uniform); duplicate f=49 compute for
    #pragma unroll    // fg>=2 slot 12 is discarded by the f<F_ store guard
    for (int i = 0; i < 13; i++) { int f = fg + 4 * i; fidx[i] = (f < F_) ? f : 49; }

    float acc[13];
    #pragma unroll
    for (int i = 0; i < 13; i++) { int f = fg + 4 * i; acc[i] = (f < F_) ? conv_b[f] : 0.f; }

    for (int k = 0; k < 9; k++) {
        const float* wk = wT + k * 5000;
        for (int e4 = 0; e4 < 25; e4++) {
            float4 h = *(const float4*)&sEmb[(li + k) * 108 + e4 * 4];
            #pragma unroll
            for (int i = 0; i < 13; i++) {     // 13 independent uniform loads batch
                float4 w = *(const float4*)&wk[fidx[i] * 100 + e4 * 4];
                acc[i] += h.x * w.x + h.y * w.y + h.z * w.z + h.w * w.w;
            }
        }
    }

    int l = l0 + li;
    if (l < LP) {
        bool valid = (l < L_);
        #pragma unroll
        for (int i = 0; i < 13; i++) {
            int f = fg + 4 * i;
            if (f < F_) {
                u16 hv = 0;
                if (valid) {
                    float e2 = __expf(2.f * acc[i]);
                    hv = f2bf((e2 - 1.f) / (e2 + 1.f));   // tanh
                }
                hp [((size_t)b * LP + l) * 64 + f] = hv;
                hpT[((size_t)b * 64 + f) * LP + l] = hv;
            }
        }
        #pragma unroll
        for (int j = 0; j < 4; j++) {
            int f = 50 + fg + 4 * j;
            if (f < 64) {
                hp [((size_t)b * LP + l) * 64 + f] = 0;
                hpT[((size_t)b * 64 + f) * LP + l] = (f == 50 && valid) ? f2bf(1.f) : (u16)0;
            }
        }
    }
}

// ---------------------------------------------------------------- flash attention
// R7 rework: (1) U4 A-frags loaded DIRECTLY from global with pad guards ->
// the 18.4KB sU4 LDS bounce deleted (it was only read once, at frag hoist).
// (2) sHp/sHt double-buffered -> ONE barrier per l-tile (commit to buf^1 and
// prefetch of lt+2 overlap compute on buf; buf^1's readers finished before
// this iteration's barrier). (3) s_setprio around MFMA clusters (T5 attn case:
// independent blocks at different phases per CU). LDS 38.9 -> 30.2 KB.
__global__ __launch_bounds__(256) void k2_attn(
    const float* __restrict__ U4_w,
    const u16* __restrict__ hp, const u16* __restrict__ hpT,
    float* __restrict__ m4t)
{
    __shared__ u16  sHp[2][32 * 72];  // [l][f] f-contig (S-GEMM B), dbuf
    __shared__ u16  sHt[2][64 * 40];  // [f][l] l-contig (PV B), dbuf
    __shared__ u16  sP [128 * 40];    // [y][l] l-contig (PV A), wave-private bands
    __shared__ float sDen[128];

    const int tid  = threadIdx.x;
    const int b    = blockIdx.y;
    const int y0   = blockIdx.x * 128;
    const int w    = tid >> 6;
    const int lane = tid & 63;
    const int l15  = lane & 15;
    const int quad = lane >> 4;

    // U4 A-frags straight from global (guards reproduce the old zero-pad:
    // cols >= 50 and rows >= Y_ are 0). One-time, 32 guarded scalar loads.
    bf16x8 fa[2][2];
    #pragma unroll
    for (int mi = 0; mi < 2; mi++) {
        int y = y0 + w * 32 + mi * 16 + l15;
        #pragma unroll
        for (int ks = 0; ks < 2; ks++) {
            bf16x8 v;
            #pragma unroll
            for (int j = 0; j < 8; j++) {
                int c = ks * 32 + quad * 8 + j;
                float x = 0.f;
                if (y < Y_ && c < F_) x = U4_w[(size_t)y * F_ + c];
                v[j] = (short)f2bf(x);
            }
            fa[mi][ks] = v;
        }
    }

    const f32x4 fz = {0.f, 0.f, 0.f, 0.f};
    f32x4 pacc[2][4];
    #pragma unroll
    for (int mi = 0; mi < 2; mi++)
        #pragma unroll
        for (int ni = 0; ni < 4; ni++) pacc[mi][ni] = fz;

    // staging coords + prefetch regs
    const int rr = tid >> 3, seg = tid & 7;      // hp tile [32][64]
    const int fr = tid >> 2, s2 = tid & 3;       // hpT tile [64][32]
    u16x8 pv, pv2;
    // preloop: load tile0 -> commit buf0 -> load tile1
    pv  = *(const u16x8*)&hp [((size_t)b * LP + rr) * 64 + seg * 8];
    pv2 = *(const u16x8*)&hpT[((size_t)b * 64 + fr) * LP + s2 * 8];
    *(u16x8*)&sHp[0][rr * 72 + seg * 8] = pv;
    *(u16x8*)&sHt[0][fr * 40 + s2 * 8] = pv2;
    {
        const int ln = 32;
        pv  = *(const u16x8*)&hp [((size_t)b * LP + ln + rr) * 64 + seg * 8];
        pv2 = *(const u16x8*)&hpT[((size_t)b * 64 + fr) * LP + ln + s2 * 8];
    }

    int cur = 0;
    for (int lt = 0; lt < 79; lt++) {
        const int l0 = lt * 32;
        __syncthreads();   // buf[cur] committed (pre-barrier), buf[cur^1] readers done

        // commit tile lt+1 into buf[cur^1]; prefetch tile lt+2 (clamped dup on tail)
        *(u16x8*)&sHp[cur ^ 1][rr * 72 + seg * 8] = pv;
        *(u16x8*)&sHt[cur ^ 1][fr * 40 + s2 * 8] = pv2;
        {
            int lnext = lt + 2; if (lnext > 78) lnext = 78;
            const int ln = lnext * 32;
            pv  = *(const u16x8*)&hp [((size_t)b * LP + ln + rr) * 64 + seg * 8];
            pv2 = *(const u16x8*)&hpT[((size_t)b * 64 + fr) * LP + ln + s2 * 8];
        }

        // S = U4p [y×64f] · hp^T [64f×l]
        f32x4 sacc[2][2];
        #pragma unroll
        for (int mi = 0; mi < 2; mi++)
            #pragma unroll
            for (int ni = 0; ni < 2; ni++) sacc[mi][ni] = fz;
        __builtin_amdgcn_s_setprio(1);
        #pragma unroll
        for (int ks = 0; ks < 2; ks++) {
            #pragma unroll
            for (int ni = 0; ni < 2; ni++) {
                bf16x8 fb = *(const bf16x8*)&sHp[cur][(ni * 16 + l15) * 72 + ks * 32 + quad * 8];
                #pragma unroll
                for (int mi = 0; mi < 2; mi++)
                    sacc[mi][ni] = MFMA_BF16(fa[mi][ks], fb, sacc[mi][ni]);
            }
        }
        __builtin_amdgcn_s_setprio(0);

        // P = exp(S), write to LDS in A-layout (rows w*32..w*32+31: WAVE-PRIVATE)
        #pragma unroll
        for (int mi = 0; mi < 2; mi++)
            #pragma unroll
            for (int ni = 0; ni < 2; ni++) {
                int lcol = ni * 16 + l15;
                bool lv = (l0 + lcol) < L_;
                #pragma unroll
                for (int r = 0; r < 4; r++) {
                    float p = lv ? __expf(sacc[mi][ni][r]) : 0.f;
                    sP[(w * 32 + mi * 16 + quad * 4 + r) * 40 + lcol] = f2bf(p);
                }
            }
        // sP wave-private; sHt[cur] was committed before this iter's barrier ->
        // wave-local lgkmcnt suffices, no block barrier (rule 18 fence follows).
        asm volatile("s_waitcnt lgkmcnt(0)" ::: "memory");
        __builtin_amdgcn_sched_barrier(0);

        // O += P [y×32l] · hp [32l×64f]
        bf16x8 fv[4];
        #pragma unroll
        for (int ni = 0; ni < 4; ni++)
            fv[ni] = *(const bf16x8*)&sHt[cur][(ni * 16 + l15) * 40 + quad * 8];
        __builtin_amdgcn_s_setprio(1);
        #pragma unroll
        for (int mi = 0; mi < 2; mi++) {
            bf16x8 fp_ = *(const bf16x8*)&sP[(w * 32 + mi * 16 + l15) * 40 + quad * 8];
            #pragma unroll
            for (int ni = 0; ni < 4; ni++)
                pacc[mi][ni] = MFMA_BF16(fp_, fv[ni], pacc[mi][ni]);
        }
        __builtin_amdgcn_s_setprio(0);
        cur ^= 1;
    }

    // denominator column: f=50 -> ni=3, lane&15==2
    if (l15 == 2) {
        #pragma unroll
        for (int mi = 0; mi < 2; mi++)
            #pragma unroll
            for (int r = 0; r < 4; r++)
                sDen[w * 32 + mi * 16 + quad * 4 + r] = pacc[mi][3][r];
    }
    __syncthreads();

    #pragma unroll
    for (int mi = 0; mi < 2; mi++)
        #pragma unroll
        for (int ni = 0; ni < 4; ni++) {
            int f = ni * 16 + l15;
            if (f < F_) {
                #pragma unroll
                for (int r = 0; r < 4; r++) {
                    int yl = w * 32 + mi * 16 + quad * 4 + r;
                    int y = y0 + yl;
                    if (y < Y_)
                        m4t[((size_t)b * Y_ + y) * F_ + f] = pacc[mi][ni][r] / sDen[yl];
                }
            }
        }
}

// ---------------------------------------------------------------- support + y4t
// Bt tile image (per kt): u16[416*32], PRE-SWIZZLED so that k4's linear
// global_load_lds image gives conflict-free ds_read_b128:
//   image[n*32 + ((z>>3) ^ ((n>>1)&3))*8 + (z&7)] = bf16(support[n][z])
__global__ __launch_bounds__(256) void k3_support(
    const float* __restrict__ m4t, const float* __restrict__ gcn_w,
    const float* __restrict__ f4t_w, const float* __restrict__ f4t_b,
    u16* __restrict__ Bt, float* __restrict__ y4t_out)
{
    __shared__ float sW[50 * 52];   // gcn_w^T : [g][f], rows padded 52
    const int tid = threadIdx.x;
    for (int i = tid; i < 50 * 52; i += 256) {
        int g = i / 52, f = i - g * 52;
        sW[i] = (f < F_) ? gcn_w[f * F_ + g] : 0.f;
    }
    __syncthreads();

    const int b = blockIdx.y;
    const int y = blockIdx.x * 256 + tid;
    if (y >= Y_) return;

    float2 m[25];
    const float* mrow = m4t + ((size_t)b * Y_ + y) * F_;
    #pragma unroll
    for (int i = 0; i < 25; i++) m[i] = *(const float2*)(mrow + 2 * i);

    const int kt = y >> 5, zo = y & 31;
    const int zhi = zo >> 3, zlo = zo & 7;
    u16* btile = Bt + (size_t)kt * (NT_ * 32);
    for (int g = 0; g < F_; g++) {
        float s = 0.f;
        const float* wr = sW + g * 52;
        #pragma unroll
        for (int i = 0; i < 25; i++) {
            float2 wv = *(const float2*)(wr + 2 * i);
            s += m[i].x * wv.x + m[i].y * wv.y;
        }
        int n = b * F_ + g;
        btile[n * 32 + ((zhi ^ ((n >> 1) & 3)) << 3) + zlo] = f2bf(s);
    }

    const float* tw = f4t_w + (size_t)y * F_;
    float acc = f4t_b[y];
    #pragma unroll
    for (int i = 0; i < 25; i++) {
        float2 wv = *(const float2*)(tw + 2 * i);
        acc += m[i].x * wv.x + m[i].y * wv.y;
    }
    y4t_out[(size_t)b * Y_ + y] = acc;
}

// ---------------------------------------------------------------- adj GEMM
// R6 structure kept: BM=128, 512-thread blocks (8 waves: 4M x 2N), grid 210,
// asymmetric counted-vmcnt pipeline (A 3-buf depth-2, B 2-buf depth-1),
// per iter issue B(t+1)[4] + A(t+2)[8] -> s_waitcnt vmcnt(20).
__global__ __launch_bounds__(512, 2) void k4_gemm(
    const float* __restrict__ adj, const u16* __restrict__ Bt,
    float* __restrict__ outp)
{
    __shared__ float sA[3][128 * 32];   // fp32 A-tiles (swizzled image), 3x16 KB
    __shared__ u16   sB[2][NT_ * 32];   // bf16 B-tiles (pre-swizzled image), 2x26 KB

    const int tid  = threadIdx.x;
    const int bid  = blockIdx.x;
    const int kp   = bid % KP_;                     // 0..2
    const int mIdx = bid / KP_;                     // 0..69
    const int m0   = mIdx * 128;
    const int w    = tid >> 6;                      // 0..7
    const int wq   = __builtin_amdgcn_readfirstlane(w);
    const int lane = tid & 63;
    const int l15  = lane & 15;
    const int quad = lane >> 4;
    const int wm   = w & 3;        // M sub-block (0..3) -> rows wm*32..+32
    const int wn   = w >> 2;       // N half (0..1) -> cols wn*208..+208

    const int rA   = tid >> 5;                                        // 0..15
    const int colA = ((((tid & 31) >> 2) ^ (rA & 7)) << 2) | (tid & 3);
    const unsigned rbaseA = (unsigned)(m0 + rA) * (unsigned)Y_ + (unsigned)colA;

    // lane-const swizzled read offsets
    const int r7    = l15 & 7;
    const int offA0 = (((2 * quad)     ^ r7) << 2);   // float offset of 1st 16B slot
    const int offA1 = (((2 * quad + 1) ^ r7) << 2);   // float offset of 2nd 16B slot
    const int offB  = ((quad ^ ((l15 >> 1) & 3)) << 3); // u16 offset of B slot

    const f32x4 fz = {0.f, 0.f, 0.f, 0.f};
    f32x4 acc[2][13];
    #pragma unroll
    for (int mi = 0; mi < 2; mi++)
        #pragma unroll
        for (int ni = 0; ni < 13; ni++) acc[mi][ni] = fz;

    auto stageB = [&](int buf, int kt) {
        const char* bt = (const char*)Bt + (size_t)kt * (NT_ * 32 * 2);
        char* sb = (char*)sB[buf];
        #pragma unroll
        for (int j = 0; j < 3; j++)
            glds16(bt + j * 8192 + tid * 16, sb + j * 8192 + wq * 1024);
        glds4(bt + 24576 + tid * 4, sb + 24576 + wq * 256);
    };
    auto stageA = [&](int buf, int kt) {
        char* sa = (char*)sA[buf];
        const unsigned idx0 = rbaseA + (unsigned)kt * 32u;
        #pragma unroll
        for (int j = 0; j < 8; j++) {
            unsigned idx = idx0 + (unsigned)(j * 16 * Y_);
            idx = (idx > (unsigned)AMAX_) ? (unsigned)AMAX_ : idx;   // OOB clamp (harmless rows/cols)
            glds4(adj + idx, sa + j * 2048 + wq * 256);
        }
    };

    // K-split: kp0 = [0,94) (94 tiles), kp1 = [94,187), kp2 = [187,280) (93 each)
    const int kt0   = (kp == 0) ? 0 : 1 + 93 * kp;
    const int niter = 93 + (kp == 0);
    const int ktmax = kt0 + niter - 1;
    // prologue issue order (vmcnt accounting depends on it): B0[4], A0[8], A1[8]
    stageB(0, kt0);
    stageA(0, kt0);
    stageA(1, kt0 + 1);

    int a0 = 0;   // A buffer index = t % 3
    for (int it = 0; it < niter; it++) {
        int ktb = kt0 + it + 1; if (ktb > ktmax) ktb = ktmax;
        int kta = kt0 + it + 2; if (kta > ktmax) kta = ktmax;
        stageB((it + 1) & 1, ktb);
        int a2 = a0 + 2; if (a2 >= 3) a2 -= 3;
        stageA(a2, kta);
        asm volatile("s_waitcnt vmcnt(20)" ::: "memory");   // B(t), A(t) landed
        __builtin_amdgcn_s_barrier();            // raw: no compiler drain
        __builtin_amdgcn_sched_barrier(0);

        const float* sAc = sA[a0];
        const u16*   sBc = sB[it & 1];
        bf16x8 fa[2];
        #pragma unroll
        for (int mi = 0; mi < 2; mi++) {
            const int rb = (wm * 32 + mi * 16 + l15) * 32;
            f32x4 x0 = *(const f32x4*)&sAc[rb + offA0];
            f32x4 x1 = *(const f32x4*)&sAc[rb + offA1];
            bf16x8 v;
            v[0] = (short)f2bf(x0[0]); v[1] = (short)f2bf(x0[1]);
            v[2] = (short)f2bf(x0[2]); v[3] = (short)f2bf(x0[3]);
            v[4] = (short)f2bf(x1[0]); v[5] = (short)f2bf(x1[1]);
            v[6] = (short)f2bf(x1[2]); v[7] = (short)f2bf(x1[3]);
            fa[mi] = v;
        }
        #pragma unroll
        for (int ni = 0; ni < 13; ni++) {
            bf16x8 fb = *(const bf16x8*)&sBc[(wn * 208 + ni * 16 + l15) * 32 + offB];
            acc[0][ni] = MFMA_BF16(fa[0], fb, acc[0][ni]);
            acc[1][ni] = MFMA_BF16(fa[1], fb, acc[1][ni]);
        }

        __builtin_amdgcn_sched_barrier(0);
        asm volatile("s_waitcnt lgkmcnt(0)" ::: "memory");   // reads of this tile done
        __builtin_amdgcn_s_barrier();            // raw: buffers free for overwrite
        __builtin_amdgcn_sched_barrier(0);       // pin next-iter glds below the barrier
        a0++; if (a0 >= 3) a0 = 0;
    }
    asm volatile("s_waitcnt vmcnt(0)" ::: "memory");   // drain dummy in-flight loads
    __builtin_amdgcn_sched_barrier(0);

    float* dst = outp + (size_t)kp * Y_ * 400;
    #pragma unroll
    for (int mi = 0; mi < 2; mi++)
        #pragma unroll
        for (int ni = 0; ni < 13; ni++) {
            int n = wn * 208 + ni * 16 + l15;
            if (n < 400) {
                #pragma unroll
                for (int r4 = 0; r4 < 4; r4++) {
                    int y = m0 + wm * 32 + mi * 16 + quad * 4 + r4;
                    if (y < Y_) dst[(size_t)y * 400 + n] = acc[mi][ni][r4];
                }
            }
        }
}

// ---------------------------------------------------------------- final y4
__global__ __launch_bounds__(256) void k5_final(
    const float* __restrict__ outp, const float* __restrict__ m4t,
    const float* __restrict__ gcn_b, const float* __restrict__ f4_w,
    const float* __restrict__ f4_b, float* __restrict__ y4_out)
{
    const int b = blockIdx.y;
    const int y = blockIdx.x * 256 + threadIdx.x;
    if (y >= Y_) return;

    const size_t PS = (size_t)Y_ * 400;
    const float* p0 = outp + (size_t)y * 400 + b * F_;
    const float* fw = f4_w + (size_t)y * 100;
    const float* mrow = m4t + ((size_t)b * Y_ + y) * F_;

    float acc = f4_b[y];
    #pragma unroll
    for (int i = 0; i < 25; i++) {
        float2 mv = *(const float2*)(mrow + 2 * i);
        float2 wv = *(const float2*)(fw + 2 * i);
        acc += mv.x * wv.x + mv.y * wv.y;
    }
    #pragma unroll
    for (int i = 0; i < 25; i++) {
        float sx = 0.f, sy = 0.f;
        #pragma unroll
        for (int kp = 0; kp < KP_; kp++) {
            float2 v = *(const float2*)(p0 + kp * PS + 2 * i);
            sx += v.x; sy += v.y;
        }
        float2 gb = *(const float2*)(gcn_b + 2 * i);
        sx += gb.x; sy += gb.y;
        sx = sx > 0.f ? sx : 0.2f * sx;   // leaky_relu
        sy = sy > 0.f ? sy : 0.2f * sy;
        float2 wv = *(const float2*)(fw + 50 + 2 * i);
        acc += sx * wv.x + sy * wv.y;
    }
    y4_out[(size_t)b * Y_ + y] = acc;
}

// ---------------------------------------------------------------- launch
extern "C" void kernel_launch(void* const* d_in, const int* in_sizes, int n_in,
                              void* d_out, int out_size, void* d_ws, size_t ws_size,
                              hipStream_t stream) {
    const int*   x       = (const int*)d_in[0];
    const float* embed_w = (const float*)d_in[2];
    const float* conv_w  = (const float*)d_in[3];
    const float* conv_b  = (const float*)d_in[4];
    const float* U4_w    = (const float*)d_in[5];
    const float* gcn_w   = (const float*)d_in[6];
    const float* gcn_b   = (const float*)d_in[7];
    const float* adj     = (const float*)d_in[8];
    const float* f4t_w   = (const float*)d_in[9];
    const float* f4t_b   = (const float*)d_in[10];
    const float* f4_w    = (const float*)d_in[11];
    const float* f4_b    = (const float*)d_in[12];
    float* out = (float*)d_out;

    char* ws = (char*)d_ws;
    const size_t SZ_WT  = 180224;                            // 9*50*100*4 rounded
    const size_t SZ_HP  = (size_t)B_ * LP * 64 * 2;          // 2,588,672
    const size_t SZ_BT  = (size_t)KT_ * NT_ * 32 * 2;        // 7,454,720
    const size_t SZ_M4T = (size_t)B_ * Y_ * F_ * 4;          // 14,275,200
    int*   flag = (int*)ws;
    float* wT   = (float*)(ws + 16);
    u16*   hp   = (u16*)(ws + 16 + SZ_WT);
    u16*   hpT  = (u16*)(ws + 16 + SZ_WT + SZ_HP);
    u16*   Bt   = (u16*)(ws + 16 + SZ_WT + 2 * SZ_HP);
    float* m4t  = (float*)(ws + 16 + SZ_WT + 2 * SZ_HP + SZ_BT);
    float* outp = (float*)(ws + 16 + SZ_WT + 2 * SZ_HP + SZ_BT + SZ_M4T);  // KP_*Y*400*4 = 43 MB

    k0_prep<<<9, 256, 0, stream>>>(x, conv_w, flag, wT);
    k1_conv<<<dim3(40, 8), 256, 0, stream>>>(x, flag, embed_w, wT, conv_b, hp, hpT);
    hipMemsetAsync(Bt, 0, SZ_BT, stream);
    k2_attn<<<dim3(70, 8), 256, 0, stream>>>(U4_w, hp, hpT, m4t);
    k3_support<<<dim3(35, 8), 256, 0, stream>>>(m4t, gcn_w, f4t_w, f4t_b, Bt, out);
    k4_gemm<<<dim3(70 * KP_), 512, 0, stream>>>(adj, Bt, outp);
    k5_final<<<dim3(35, 8), 256, 0, stream>>>(outp, m4t, gcn_b, f4_w, f4_b,
                                              out + (size_t)B_ * Y_);
}